// Round 11
// baseline (239.325 us; speedup 1.0000x reference)
//
#include <hip/hip_runtime.h>

#define N_NODES   100000
#define N_EDGES   1600000
#define D         128
#define NUM_GRAPHS 128

#define NB          196     // dst buckets (512 nodes each)
#define BUCKET_NODES 512
#define BUCKET_CAP  10240
#define EPB         8192    // edges per binplace block

#define N_TILES32   3125    // 100000 / 32 exactly
#define GEMM_BLOCKS 782     // 782 * 4 waves = 3128 >= 3125

typedef __attribute__((ext_vector_type(8)))  short bf16x8;
typedef __attribute__((ext_vector_type(8)))  unsigned short u16x8;
typedef __attribute__((ext_vector_type(4)))  unsigned short u16x4;
typedef __attribute__((ext_vector_type(16))) float f32x16;

__device__ __forceinline__ float bf2f(unsigned short v) {
    return __uint_as_float(((unsigned int)v) << 16);
}
__device__ __forceinline__ unsigned short f2bf(float f) {
    unsigned int u = __float_as_uint(f);
    u = (u + 0x7FFFu + ((u >> 16) & 1u)) >> 16;
    return (unsigned short)u;
}

// ---------------- edge binning: counting-sort into 196 bucket regions ----------------
__global__ __launch_bounds__(256) void k_binplace(const int* __restrict__ src,
                                                  const int* __restrict__ dst,
                                                  int* __restrict__ gcur,
                                                  unsigned int* __restrict__ binned) {
    __shared__ unsigned int stag[EPB];       // 32 KB
    __shared__ unsigned char sbk[EPB];       // 8 KB
    __shared__ int hist[NB], lstart[NB], lcur[NB], gclaim[NB];
    __shared__ int scan[256];
    const int t = threadIdx.x;
    const int e0 = blockIdx.x * EPB;

    if (t < NB) hist[t] = 0;
    __syncthreads();

    int pk[32]; int bk[32];
#pragma unroll
    for (int i = 0; i < 32; ++i) {
        int e = e0 + t + 256 * i;
        if (e < N_EDGES) {
            int s = src[e], d = dst[e];
            bk[i] = d >> 9;
            pk[i] = (s << 9) | (d & 511);
            atomicAdd(&hist[bk[i]], 1);
        } else {
            bk[i] = -1; pk[i] = 0;
        }
    }
    __syncthreads();

    int hv = (t < NB) ? hist[t] : 0;
    scan[t] = hv;
    __syncthreads();
    for (int off = 1; off < 256; off <<= 1) {
        int add = (t >= off) ? scan[t - off] : 0;
        __syncthreads();
        scan[t] += add;
        __syncthreads();
    }
    if (t < NB) {
        int ex = scan[t] - hv;
        lstart[t] = ex;
        lcur[t]   = ex;
        gclaim[t] = atomicAdd(&gcur[t], hv);
    }
    __syncthreads();

#pragma unroll
    for (int i = 0; i < 32; ++i) {
        if (bk[i] >= 0) {
            int p = atomicAdd(&lcur[bk[i]], 1);
            stag[p] = (unsigned int)pk[i];
            sbk[p] = (unsigned char)bk[i];
        }
    }
    __syncthreads();

    const int total = scan[NB - 1];
    for (int j = t; j < total; j += 256) {
        int b = sbk[j];
        binned[(size_t)b * BUCKET_CAP + gclaim[b] + (j - lstart[b])] = stag[j];
    }
}

// ---------------- per-bucket CSR finalize ----------------
__global__ __launch_bounds__(256) void k_fill2(const unsigned int* __restrict__ binned,
                                               const int* __restrict__ gcur,
                                               int* __restrict__ adj,
                                               int* __restrict__ row_start,
                                               int* __restrict__ row_len) {
    __shared__ int hist[BUCKET_NODES], lstart[BUCKET_NODES], lcur[BUCKET_NODES];
    __shared__ int s2[256];
    const int t = threadIdx.x;
    const int b = blockIdx.x;
    const int C = gcur[b];
    const unsigned int* bp = binned + (size_t)b * BUCKET_CAP;

    hist[t] = 0; hist[t + 256] = 0;
    __syncthreads();
    for (int j = t; j < C; j += 256)
        atomicAdd(&hist[bp[j] & 511], 1);
    __syncthreads();

    int h0 = hist[2 * t], h1 = hist[2 * t + 1];
    int sv = h0 + h1;
    s2[t] = sv;
    __syncthreads();
    for (int off = 1; off < 256; off <<= 1) {
        int add = (t >= off) ? s2[t - off] : 0;
        __syncthreads();
        s2[t] += add;
        __syncthreads();
    }
    int ex = s2[t] - sv;
    lstart[2 * t] = ex;          lcur[2 * t] = ex;
    lstart[2 * t + 1] = ex + h0; lcur[2 * t + 1] = ex + h0;
    __syncthreads();

    for (int dl = t; dl < BUCKET_NODES; dl += 256) {
        int n = b * BUCKET_NODES + dl;
        if (n < N_NODES) {
            row_start[n] = b * BUCKET_CAP + lstart[dl];
            row_len[n]   = hist[dl];
        }
    }

    for (int j = t; j < C; j += 256) {
        unsigned int v = bp[j];
        int dl = v & 511;
        int pos = atomicAdd(&lcur[dl], 1);
        adj[(size_t)b * BUCKET_CAP + pos] = (int)(v >> 9);
    }
}

// graph_ids SORTED -> per-graph count via binary search
__global__ void k_gcnt_bs(const int* __restrict__ gid, int* __restrict__ gcnt) {
    int g = threadIdx.x;
    if (g >= NUM_GRAPHS) return;
    int lo = 0, hi = N_NODES;
    while (lo < hi) { int mid = (lo + hi) >> 1; if (gid[mid] < g) lo = mid + 1; else hi = mid; }
    int beg = lo;
    hi = N_NODES;
    while (lo < hi) { int mid = (lo + hi) >> 1; if (gid[mid] < g + 1) lo = mid + 1; else hi = mid; }
    gcnt[g] = lo - beg;
}

// ---------------- casts / weight prep ----------------

__global__ void k_cast_h(const float* __restrict__ h, unsigned short* __restrict__ hb) {
    int i = blockIdx.x * 256 + threadIdx.x;
    if (i >= N_NODES * (D / 8)) return;
    const float4* hv = (const float4*)h;
    float4 x = hv[2 * i], y = hv[2 * i + 1];
    u16x8 p;
    p[0] = f2bf(x.x); p[1] = f2bf(x.y); p[2] = f2bf(x.z); p[3] = f2bf(x.w);
    p[4] = f2bf(y.x); p[5] = f2bf(y.y); p[6] = f2bf(y.z); p[7] = f2bf(y.w);
    *(u16x8*)(hb + (size_t)i * 8) = p;
}

// 32x32 fragment-linear weight prep:
//   Wtp[((ct*16+kt)*64 + lane)*8 + j] = W[k][n]
//   n = ct*32 + (lane&31), k = kt*16 + 8*(lane>>5) + j  (k<128 -> Ws, else Wn[k-128])
__global__ void k_prep_w1(const float* __restrict__ Ws, const float* __restrict__ Wn,
                          unsigned short* __restrict__ Wtp) {
    int idx = blockIdx.x * 256 + threadIdx.x;  // 32768
    if (idx >= D * 256) return;
    int j  = idx & 7;
    int l  = (idx >> 3) & 63;
    int fs = idx >> 9;               // ct*16 + kt
    int ct = fs >> 4, kt = fs & 15;
    int n  = ct * 32 + (l & 31);
    int k  = kt * 16 + 8 * (l >> 5) + j;
    float v = (k < 128) ? Ws[k * D + n] : Wn[(k - 128) * D + n];
    Wtp[idx] = f2bf(v);
}

// Layer-1 output stored with column permutation sigma(c) = (c&31)*4 + (c>>5),
// so stored position p holds true col c(p) = 32*(p&3) + (p>>2).
// Layer-2 K axis maps through sigma^-1 (same for self & neigh halves).
__global__ void k_prep_w2(const float* __restrict__ Ws, const float* __restrict__ Wn,
                          unsigned short* __restrict__ Wtp) {
    int idx = blockIdx.x * 256 + threadIdx.x;  // 32768
    if (idx >= D * 256) return;
    int j  = idx & 7;
    int l  = (idx >> 3) & 63;
    int fs = idx >> 9;
    int ct = fs >> 4, kt = fs & 15;
    int n  = ct * 32 + (l & 31);
    int k  = kt * 16 + 8 * (l >> 5) + j;   // 0..255
    int p  = k & 127;
    int c  = 32 * (p & 3) + (p >> 2);      // true column
    float v = (k < 128) ? Ws[c * D + n] : Wn[c * D + n];
    Wtp[idx] = f2bf(v);
}

// ---------------- mean aggregation, bf16 gather (16 threads / node), 8-edge unroll ----
// VGPR budget is tiny (28 at 4-unroll) -> deepen MLP: 8 outstanding 16B loads/lane.
__global__ __launch_bounds__(256) void k_agg_bf(const unsigned short* __restrict__ hin,
                                                const int* __restrict__ row_start,
                                                const int* __restrict__ row_len,
                                                const int* __restrict__ adj,
                                                unsigned short* __restrict__ hout) {
    int node = blockIdx.x * 16 + (threadIdx.x >> 4);
    int sub = threadIdx.x & 15;
    if (node >= N_NODES) return;
    int beg = row_start[node];
    int len = row_len[node];
    int end = beg + len;
    const unsigned short* hsub = hin + sub * 8;
    float acc[8];
#pragma unroll
    for (int i = 0; i < 8; ++i) acc[i] = 0.f;
    int j = beg;
    for (; j + 7 < end; j += 8) {
        int s0 = adj[j],     s1 = adj[j + 1], s2 = adj[j + 2], s3 = adj[j + 3];
        int s4 = adj[j + 4], s5 = adj[j + 5], s6 = adj[j + 6], s7 = adj[j + 7];
        u16x8 v0 = *(const u16x8*)(hsub + (size_t)s0 * D);
        u16x8 v1 = *(const u16x8*)(hsub + (size_t)s1 * D);
        u16x8 v2 = *(const u16x8*)(hsub + (size_t)s2 * D);
        u16x8 v3 = *(const u16x8*)(hsub + (size_t)s3 * D);
        u16x8 v4 = *(const u16x8*)(hsub + (size_t)s4 * D);
        u16x8 v5 = *(const u16x8*)(hsub + (size_t)s5 * D);
        u16x8 v6 = *(const u16x8*)(hsub + (size_t)s6 * D);
        u16x8 v7 = *(const u16x8*)(hsub + (size_t)s7 * D);
#pragma unroll
        for (int i = 0; i < 8; ++i)
            acc[i] += ((bf2f(v0[i]) + bf2f(v1[i])) + (bf2f(v2[i]) + bf2f(v3[i])))
                    + ((bf2f(v4[i]) + bf2f(v5[i])) + (bf2f(v6[i]) + bf2f(v7[i])));
    }
    for (; j + 3 < end; j += 4) {
        int s0 = adj[j], s1 = adj[j + 1], s2 = adj[j + 2], s3 = adj[j + 3];
        u16x8 v0 = *(const u16x8*)(hsub + (size_t)s0 * D);
        u16x8 v1 = *(const u16x8*)(hsub + (size_t)s1 * D);
        u16x8 v2 = *(const u16x8*)(hsub + (size_t)s2 * D);
        u16x8 v3 = *(const u16x8*)(hsub + (size_t)s3 * D);
#pragma unroll
        for (int i = 0; i < 8; ++i)
            acc[i] += (bf2f(v0[i]) + bf2f(v1[i])) + (bf2f(v2[i]) + bf2f(v3[i]));
    }
    for (; j < end; ++j) {
        int s0 = adj[j];
        u16x8 v0 = *(const u16x8*)(hsub + (size_t)s0 * D);
#pragma unroll
        for (int i = 0; i < 8; ++i) acc[i] += bf2f(v0[i]);
    }
    float inv = (len > 0) ? 1.f / (float)len : 0.f;
    u16x8 p;
#pragma unroll
    for (int i = 0; i < 8; ++i) p[i] = f2bf(acc[i] * inv);
    *(u16x8*)(hout + (size_t)node * D + sub * 8) = p;
}

// ---------------- MFMA GEMM: 32x32x16, 32 rows/wave, LDS-staged B ----------------
// 782 blocks x 4 waves = 3128 waves; wave gw owns 32-row tile gw (3125 tiles exact).
// A-frag: row = lane&31, k = kt*16 + 8*(lane>>5) + j.
// C/D:    col = lane&31, row = (reg&3) + 8*(reg>>2) + 4*(lane>>5).
// POOL=0: store permuted cols sigma(c)=(c&31)*4+(c>>5): lane's 4 ct-values = one 8B store/row.
// POOL=1: run-compressed per-graph atomics at true cols.
template <int POOL>
__global__ __launch_bounds__(256) void k_gemm_mfma(
    const unsigned short* __restrict__ X0, const unsigned short* __restrict__ X1,
    const unsigned short* __restrict__ Wtp, const float* __restrict__ bias,
    unsigned short* __restrict__ outp,
    const int* __restrict__ gid, float* __restrict__ gsum) {
    __shared__ unsigned short WS[D * 256];   // 64 KB
    const int tid = threadIdx.x;
    const int wave = tid >> 6, lane = tid & 63;
    const int l31 = lane & 31, half = lane >> 5;
    const int gw = blockIdx.x * 4 + wave;    // 32-row tile id
    const bool act = (gw < N_TILES32);

    // A fragments first (latency hidden under staging barrier)
    bf16x8 a[16];
    if (act) {
        const int row = gw * 32 + l31;
        const unsigned short* x0 = X0 + (size_t)row * D + half * 8;
        const unsigned short* x1 = X1 + (size_t)row * D + half * 8;
#pragma unroll
        for (int kt = 0; kt < 8; ++kt)
            a[kt] = *(const bf16x8*)(x0 + kt * 16);
#pragma unroll
        for (int kt = 0; kt < 8; ++kt)
            a[8 + kt] = *(const bf16x8*)(x1 + kt * 16);
    }

    // stage weights -> LDS (64 KB linear)
    {
        const u16x8* g = (const u16x8*)Wtp;
        u16x8* s = (u16x8*)WS;
#pragma unroll
        for (int i = 0; i < 16; ++i) s[i * 256 + tid] = g[i * 256 + tid];
    }
    __syncthreads();
    if (!act) return;

    f32x16 acc[4];
#pragma unroll
    for (int ct = 0; ct < 4; ++ct)
#pragma unroll
        for (int i = 0; i < 16; ++i) acc[ct][i] = 0.f;

    // 2 ct-chains interleaved per pass for ILP
#pragma unroll
    for (int cp = 0; cp < 2; ++cp) {
        const int c0 = 2 * cp, c1 = 2 * cp + 1;
#pragma unroll
        for (int kt = 0; kt < 16; ++kt) {
            bf16x8 b0 = *(const bf16x8*)&WS[((c0 * 16 + kt) * 64 + lane) * 8];
            bf16x8 b1 = *(const bf16x8*)&WS[((c1 * 16 + kt) * 64 + lane) * 8];
            acc[c0] = __builtin_amdgcn_mfma_f32_32x32x16_bf16(a[kt], b0, acc[c0], 0, 0, 0);
            acc[c1] = __builtin_amdgcn_mfma_f32_32x32x16_bf16(a[kt], b1, acc[c1], 0, 0, 0);
        }
    }

    const int trow0 = gw * 32;
    float bia[4];
#pragma unroll
    for (int ct = 0; ct < 4; ++ct) bia[ct] = bias[ct * 32 + l31];

    if (POOL == 0) {
#pragma unroll
        for (int r = 0; r < 16; ++r) {
            int row = trow0 + (r & 3) + 8 * (r >> 2) + 4 * half;
            u16x4 pk;
#pragma unroll
            for (int ct = 0; ct < 4; ++ct)
                pk[ct] = f2bf(fmaxf(acc[ct][r] + bia[ct], 0.f));
            *(u16x4*)(outp + (size_t)row * D + l31 * 4) = pk;
        }
    } else {
        int g[16];
#pragma unroll
        for (int r = 0; r < 16; ++r)
            g[r] = gid[trow0 + (r & 3) + 8 * (r >> 2) + 4 * half];
#pragma unroll
        for (int ct = 0; ct < 4; ++ct) {
            int c = ct * 32 + l31;
            float run = 0.f; int curg = -1;
#pragma unroll
            for (int r = 0; r < 16; ++r) {
                float v = fmaxf(acc[ct][r] + bia[ct], 0.f);
                if (g[r] != curg) {
                    if (curg >= 0) atomicAdd(&gsum[curg * D + c], run);
                    curg = g[r]; run = v;
                } else {
                    run += v;
                }
            }
            if (curg >= 0) atomicAdd(&gsum[curg * D + c], run);
        }
    }
}

// ---------------- final divide ----------------
__global__ void k_final(const float* __restrict__ gsum, const int* __restrict__ gcnt,
                        float* __restrict__ out) {
    int i = blockIdx.x * blockDim.x + threadIdx.x;
    if (i < NUM_GRAPHS * D) {
        int g = i >> 7;
        int c = gcnt[g];
        out[i] = gsum[i] / (float)(c > 0 ? c : 1);
    }
}

// ---------------- launch ----------------
extern "C" void kernel_launch(void* const* d_in, const int* in_sizes, int n_in,
                              void* d_out, int out_size, void* d_ws, size_t ws_size,
                              hipStream_t stream) {
    const float* h   = (const float*)d_in[0];
    const float* W1s = (const float*)d_in[1];
    const float* W1n = (const float*)d_in[2];
    const float* b1  = (const float*)d_in[3];
    const float* W2s = (const float*)d_in[4];
    const float* W2n = (const float*)d_in[5];
    const float* b2  = (const float*)d_in[6];
    const int* src   = (const int*)d_in[7];
    const int* dst   = (const int*)d_in[8];
    const int* gids  = (const int*)d_in[9];
    float* out = (float*)d_out;
    char* ws = (char*)d_ws;

    size_t off = 0;
    auto alloc = [&](size_t bytes) {
        size_t o = off;
        off = (off + bytes + 255) & ~(size_t)255;
        return o;
    };
    // zeroed region (one memset)
    size_t z0         = off;
    size_t gcur_off   = alloc((size_t)NB * 4);
    size_t gsum_off   = alloc((size_t)NUM_GRAPHS * D * 4);
    size_t zlen       = off - z0;
    size_t gcnt_off   = alloc((size_t)NUM_GRAPHS * 4);
    size_t rs_off     = alloc((size_t)N_NODES * 4);
    size_t rl_off     = alloc((size_t)N_NODES * 4);
    size_t bin_off    = alloc((size_t)NB * BUCKET_CAP * 4);
    size_t adj_off    = alloc((size_t)NB * BUCKET_CAP * 4);
    size_t hb_off     = alloc((size_t)N_NODES * D * 2);
    size_t hn_off     = alloc((size_t)N_NODES * D * 2);
    size_t h1_off     = alloc((size_t)N_NODES * D * 2);
    size_t wt1_off    = alloc((size_t)D * 256 * 2);
    size_t wt2_off    = alloc((size_t)D * 256 * 2);
    (void)ws_size;

    int*   gcur      = (int*)(ws + gcur_off);
    int*   gcnt      = (int*)(ws + gcnt_off);
    float* gsum      = (float*)(ws + gsum_off);
    int*   row_start = (int*)(ws + rs_off);
    int*   row_len   = (int*)(ws + rl_off);
    unsigned int* binned = (unsigned int*)(ws + bin_off);
    int*   adj       = (int*)(ws + adj_off);
    unsigned short* hb  = (unsigned short*)(ws + hb_off);
    unsigned short* hn  = (unsigned short*)(ws + hn_off);
    unsigned short* h1p = (unsigned short*)(ws + h1_off);
    unsigned short* Wt1 = (unsigned short*)(ws + wt1_off);
    unsigned short* Wt2 = (unsigned short*)(ws + wt2_off);

    hipMemsetAsync(ws + z0, 0, zlen, stream);

    const int nbin_blocks = (N_EDGES + EPB - 1) / EPB;   // 196

    k_binplace<<<nbin_blocks, 256, 0, stream>>>(src, dst, gcur, binned);
    k_fill2<<<NB, 256, 0, stream>>>(binned, gcur, adj, row_start, row_len);
    k_gcnt_bs<<<1, 128, 0, stream>>>(gids, gcnt);

    k_cast_h<<<(N_NODES * (D / 8) + 255) / 256, 256, 0, stream>>>(h, hb);
    k_prep_w1<<<(D * 256 + 255) / 256, 256, 0, stream>>>(W1s, W1n, Wt1);
    k_prep_w2<<<(D * 256 + 255) / 256, 256, 0, stream>>>(W2s, W2n, Wt2);

    const int agg_blocks = (N_NODES + 15) / 16;    // 6250

    // layer 1
    k_agg_bf<<<agg_blocks, 256, 0, stream>>>(hb, row_start, row_len, adj, hn);
    k_gemm_mfma<0><<<GEMM_BLOCKS, 256, 0, stream>>>(hb, hn, Wt1, b1, h1p, nullptr, nullptr);
    // layer 2 (pool fused into epilogue)
    k_agg_bf<<<agg_blocks, 256, 0, stream>>>(h1p, row_start, row_len, adj, hn);
    k_gemm_mfma<1><<<GEMM_BLOCKS, 256, 0, stream>>>(h1p, hn, Wt2, b2, nullptr, gids, gsum);

    k_final<<<(NUM_GRAPHS * D + 255) / 256, 256, 0, stream>>>(gsum, gcnt, out);
}

// Round 12
// 195.378 us; speedup vs baseline: 1.2249x; 1.2249x over previous
//
#include <hip/hip_runtime.h>

#define N_NODES   100000
#define N_EDGES   1600000
#define D         128
#define NUM_GRAPHS 128

#define NB          196     // dst buckets (512 nodes each)
#define BUCKET_NODES 512
#define BUCKET_CAP  10240
#define EPB         8192    // edges per binplace block

#define N_TILES32   3125    // 100000 / 32 exactly
#define GEMM_BLOCKS 782     // 782 * 4 waves = 3128 >= 3125

typedef __attribute__((ext_vector_type(8)))  short bf16x8;
typedef __attribute__((ext_vector_type(8)))  unsigned short u16x8;
typedef __attribute__((ext_vector_type(4)))  unsigned short u16x4;
typedef __attribute__((ext_vector_type(2)))  unsigned int u32x2;
typedef __attribute__((ext_vector_type(16))) float f32x16;

__device__ __forceinline__ float bf2f(unsigned short v) {
    return __uint_as_float(((unsigned int)v) << 16);
}
__device__ __forceinline__ unsigned short f2bf(float f) {
    unsigned int u = __float_as_uint(f);
    u = (u + 0x7FFFu + ((u >> 16) & 1u)) >> 16;
    return (unsigned short)u;
}

// accumulate 8 fp8 (e4m3) values from an 8-byte word pair into acc[0..7]
__device__ __forceinline__ void acc_f8(float* acc, u32x2 v) {
    auto a0 = __builtin_amdgcn_cvt_pk_f32_fp8((int)v[0], false);
    auto a1 = __builtin_amdgcn_cvt_pk_f32_fp8((int)v[0], true);
    auto a2 = __builtin_amdgcn_cvt_pk_f32_fp8((int)v[1], false);
    auto a3 = __builtin_amdgcn_cvt_pk_f32_fp8((int)v[1], true);
    acc[0] += a0[0]; acc[1] += a0[1]; acc[2] += a1[0]; acc[3] += a1[1];
    acc[4] += a2[0]; acc[5] += a2[1]; acc[6] += a3[0]; acc[7] += a3[1];
}

// ---------------- edge binning: counting-sort into 196 bucket regions ----------------
__global__ __launch_bounds__(256) void k_binplace(const int* __restrict__ src,
                                                  const int* __restrict__ dst,
                                                  int* __restrict__ gcur,
                                                  unsigned int* __restrict__ binned) {
    __shared__ unsigned int stag[EPB];       // 32 KB
    __shared__ unsigned char sbk[EPB];       // 8 KB
    __shared__ int hist[NB], lstart[NB], lcur[NB], gclaim[NB];
    __shared__ int scan[256];
    const int t = threadIdx.x;
    const int e0 = blockIdx.x * EPB;

    if (t < NB) hist[t] = 0;
    __syncthreads();

    int pk[32]; int bk[32];
#pragma unroll
    for (int i = 0; i < 32; ++i) {
        int e = e0 + t + 256 * i;
        if (e < N_EDGES) {
            int s = src[e], d = dst[e];
            bk[i] = d >> 9;
            pk[i] = (s << 9) | (d & 511);
            atomicAdd(&hist[bk[i]], 1);
        } else {
            bk[i] = -1; pk[i] = 0;
        }
    }
    __syncthreads();

    int hv = (t < NB) ? hist[t] : 0;
    scan[t] = hv;
    __syncthreads();
    for (int off = 1; off < 256; off <<= 1) {
        int add = (t >= off) ? scan[t - off] : 0;
        __syncthreads();
        scan[t] += add;
        __syncthreads();
    }
    if (t < NB) {
        int ex = scan[t] - hv;
        lstart[t] = ex;
        lcur[t]   = ex;
        gclaim[t] = atomicAdd(&gcur[t], hv);
    }
    __syncthreads();

#pragma unroll
    for (int i = 0; i < 32; ++i) {
        if (bk[i] >= 0) {
            int p = atomicAdd(&lcur[bk[i]], 1);
            stag[p] = (unsigned int)pk[i];
            sbk[p] = (unsigned char)bk[i];
        }
    }
    __syncthreads();

    const int total = scan[NB - 1];
    for (int j = t; j < total; j += 256) {
        int b = sbk[j];
        binned[(size_t)b * BUCKET_CAP + gclaim[b] + (j - lstart[b])] = stag[j];
    }
}

// ---------------- per-bucket CSR finalize ----------------
__global__ __launch_bounds__(256) void k_fill2(const unsigned int* __restrict__ binned,
                                               const int* __restrict__ gcur,
                                               int* __restrict__ adj,
                                               int* __restrict__ row_start,
                                               int* __restrict__ row_len) {
    __shared__ int hist[BUCKET_NODES], lstart[BUCKET_NODES], lcur[BUCKET_NODES];
    __shared__ int s2[256];
    const int t = threadIdx.x;
    const int b = blockIdx.x;
    const int C = gcur[b];
    const unsigned int* bp = binned + (size_t)b * BUCKET_CAP;

    hist[t] = 0; hist[t + 256] = 0;
    __syncthreads();
    for (int j = t; j < C; j += 256)
        atomicAdd(&hist[bp[j] & 511], 1);
    __syncthreads();

    int h0 = hist[2 * t], h1 = hist[2 * t + 1];
    int sv = h0 + h1;
    s2[t] = sv;
    __syncthreads();
    for (int off = 1; off < 256; off <<= 1) {
        int add = (t >= off) ? s2[t - off] : 0;
        __syncthreads();
        s2[t] += add;
        __syncthreads();
    }
    int ex = s2[t] - sv;
    lstart[2 * t] = ex;          lcur[2 * t] = ex;
    lstart[2 * t + 1] = ex + h0; lcur[2 * t + 1] = ex + h0;
    __syncthreads();

    for (int dl = t; dl < BUCKET_NODES; dl += 256) {
        int n = b * BUCKET_NODES + dl;
        if (n < N_NODES) {
            row_start[n] = b * BUCKET_CAP + lstart[dl];
            row_len[n]   = hist[dl];
        }
    }

    for (int j = t; j < C; j += 256) {
        unsigned int v = bp[j];
        int dl = v & 511;
        int pos = atomicAdd(&lcur[dl], 1);
        adj[(size_t)b * BUCKET_CAP + pos] = (int)(v >> 9);
    }
}

// graph_ids SORTED -> per-graph count via binary search
__global__ void k_gcnt_bs(const int* __restrict__ gid, int* __restrict__ gcnt) {
    int g = threadIdx.x;
    if (g >= NUM_GRAPHS) return;
    int lo = 0, hi = N_NODES;
    while (lo < hi) { int mid = (lo + hi) >> 1; if (gid[mid] < g) lo = mid + 1; else hi = mid; }
    int beg = lo;
    hi = N_NODES;
    while (lo < hi) { int mid = (lo + hi) >> 1; if (gid[mid] < g + 1) lo = mid + 1; else hi = mid; }
    gcnt[g] = lo - beg;
}

// ---------------- casts / weight prep ----------------

// h fp32 -> bf16 (GEMM self path) + fp8 e4m3 (gather path)
__global__ void k_cast_h(const float* __restrict__ h, unsigned short* __restrict__ hb,
                         unsigned char* __restrict__ h8) {
    int i = blockIdx.x * 256 + threadIdx.x;
    if (i >= N_NODES * (D / 8)) return;
    const float4* hv = (const float4*)h;
    float4 x = hv[2 * i], y = hv[2 * i + 1];
    u16x8 p;
    p[0] = f2bf(x.x); p[1] = f2bf(x.y); p[2] = f2bf(x.z); p[3] = f2bf(x.w);
    p[4] = f2bf(y.x); p[5] = f2bf(y.y); p[6] = f2bf(y.z); p[7] = f2bf(y.w);
    *(u16x8*)(hb + (size_t)i * 8) = p;
    int lo = __builtin_amdgcn_cvt_pk_fp8_f32(x.x, x.y, 0, false);
    lo = __builtin_amdgcn_cvt_pk_fp8_f32(x.z, x.w, lo, true);
    int hi = __builtin_amdgcn_cvt_pk_fp8_f32(y.x, y.y, 0, false);
    hi = __builtin_amdgcn_cvt_pk_fp8_f32(y.z, y.w, hi, true);
    u32x2 q; q[0] = (unsigned int)lo; q[1] = (unsigned int)hi;
    *(u32x2*)(h8 + (size_t)i * 8) = q;
}

// 32x32 fragment-linear weight prep:
//   Wtp[((ct*16+kt)*64 + lane)*8 + j] = W[k][n]
//   n = ct*32 + (lane&31), k = kt*16 + 8*(lane>>5) + j  (k<128 -> Ws, else Wn[k-128])
__global__ void k_prep_w1(const float* __restrict__ Ws, const float* __restrict__ Wn,
                          unsigned short* __restrict__ Wtp) {
    int idx = blockIdx.x * 256 + threadIdx.x;  // 32768
    if (idx >= D * 256) return;
    int j  = idx & 7;
    int l  = (idx >> 3) & 63;
    int fs = idx >> 9;               // ct*16 + kt
    int ct = fs >> 4, kt = fs & 15;
    int n  = ct * 32 + (l & 31);
    int k  = kt * 16 + 8 * (l >> 5) + j;
    float v = (k < 128) ? Ws[k * D + n] : Wn[(k - 128) * D + n];
    Wtp[idx] = f2bf(v);
}

// Layer-1 output stored with column permutation sigma(c) = (c&31)*4 + (c>>5),
// so stored position p holds true col c(p) = 32*(p&3) + (p>>2).
// Layer-2 K axis maps through sigma^-1 (same for self & neigh halves).
__global__ void k_prep_w2(const float* __restrict__ Ws, const float* __restrict__ Wn,
                          unsigned short* __restrict__ Wtp) {
    int idx = blockIdx.x * 256 + threadIdx.x;  // 32768
    if (idx >= D * 256) return;
    int j  = idx & 7;
    int l  = (idx >> 3) & 63;
    int fs = idx >> 9;
    int ct = fs >> 4, kt = fs & 15;
    int n  = ct * 32 + (l & 31);
    int k  = kt * 16 + 8 * (l >> 5) + j;   // 0..255
    int p  = k & 127;
    int c  = 32 * (p & 3) + (p >> 2);      // true column
    float v = (k < 128) ? Ws[c * D + n] : Wn[c * D + n];
    Wtp[idx] = f2bf(v);
}

// ---------------- mean aggregation, fp8 gather (16 lanes/node x 8 B), 8-edge unroll ----
__global__ __launch_bounds__(256) void k_agg_f8(const unsigned char* __restrict__ hin,
                                                const int* __restrict__ row_start,
                                                const int* __restrict__ row_len,
                                                const int* __restrict__ adj,
                                                unsigned short* __restrict__ hout) {
    int node = blockIdx.x * 16 + (threadIdx.x >> 4);
    int sub = threadIdx.x & 15;
    if (node >= N_NODES) return;
    int beg = row_start[node];
    int len = row_len[node];
    int end = beg + len;
    const unsigned char* hsub = hin + sub * 8;   // row stride = D bytes (fp8)
    float acc[8];
#pragma unroll
    for (int i = 0; i < 8; ++i) acc[i] = 0.f;
    int j = beg;
    for (; j + 7 < end; j += 8) {
        u32x2 v0 = *(const u32x2*)(hsub + (size_t)adj[j]     * D);
        u32x2 v1 = *(const u32x2*)(hsub + (size_t)adj[j + 1] * D);
        u32x2 v2 = *(const u32x2*)(hsub + (size_t)adj[j + 2] * D);
        u32x2 v3 = *(const u32x2*)(hsub + (size_t)adj[j + 3] * D);
        u32x2 v4 = *(const u32x2*)(hsub + (size_t)adj[j + 4] * D);
        u32x2 v5 = *(const u32x2*)(hsub + (size_t)adj[j + 5] * D);
        u32x2 v6 = *(const u32x2*)(hsub + (size_t)adj[j + 6] * D);
        u32x2 v7 = *(const u32x2*)(hsub + (size_t)adj[j + 7] * D);
        acc_f8(acc, v0); acc_f8(acc, v1); acc_f8(acc, v2); acc_f8(acc, v3);
        acc_f8(acc, v4); acc_f8(acc, v5); acc_f8(acc, v6); acc_f8(acc, v7);
    }
    for (; j + 3 < end; j += 4) {
        u32x2 v0 = *(const u32x2*)(hsub + (size_t)adj[j]     * D);
        u32x2 v1 = *(const u32x2*)(hsub + (size_t)adj[j + 1] * D);
        u32x2 v2 = *(const u32x2*)(hsub + (size_t)adj[j + 2] * D);
        u32x2 v3 = *(const u32x2*)(hsub + (size_t)adj[j + 3] * D);
        acc_f8(acc, v0); acc_f8(acc, v1); acc_f8(acc, v2); acc_f8(acc, v3);
    }
    for (; j < end; ++j) {
        u32x2 v0 = *(const u32x2*)(hsub + (size_t)adj[j] * D);
        acc_f8(acc, v0);
    }
    float inv = (len > 0) ? 1.f / (float)len : 0.f;
    u16x8 p;
#pragma unroll
    for (int i = 0; i < 8; ++i) p[i] = f2bf(acc[i] * inv);
    *(u16x8*)(hout + (size_t)node * D + sub * 8) = p;
}

// ---------------- MFMA GEMM: 32x32x16, 32 rows/wave, LDS-staged B ----------------
// 782 blocks x 4 waves = 3128 waves; wave gw owns 32-row tile gw (3125 tiles exact).
// A-frag: row = lane&31, k = kt*16 + 8*(lane>>5) + j.
// C/D:    col = lane&31, row = (reg&3) + 8*(reg>>2) + 4*(lane>>5).
// POOL=0: store permuted cols sigma(c)=(c&31)*4+(c>>5) as bf16 (8B/row/lane)
//         PLUS fp8 copy (4B/row/lane) for the layer-2 gather.
// POOL=1: run-compressed per-graph atomics at true cols.
template <int POOL>
__global__ __launch_bounds__(256) void k_gemm_mfma(
    const unsigned short* __restrict__ X0, const unsigned short* __restrict__ X1,
    const unsigned short* __restrict__ Wtp, const float* __restrict__ bias,
    unsigned short* __restrict__ outp, unsigned char* __restrict__ outp8,
    const int* __restrict__ gid, float* __restrict__ gsum) {
    __shared__ unsigned short WS[D * 256];   // 64 KB
    const int tid = threadIdx.x;
    const int wave = tid >> 6, lane = tid & 63;
    const int l31 = lane & 31, half = lane >> 5;
    const int gw = blockIdx.x * 4 + wave;    // 32-row tile id
    const bool act = (gw < N_TILES32);

    // A fragments first (latency hidden under staging barrier)
    bf16x8 a[16];
    if (act) {
        const int row = gw * 32 + l31;
        const unsigned short* x0 = X0 + (size_t)row * D + half * 8;
        const unsigned short* x1 = X1 + (size_t)row * D + half * 8;
#pragma unroll
        for (int kt = 0; kt < 8; ++kt)
            a[kt] = *(const bf16x8*)(x0 + kt * 16);
#pragma unroll
        for (int kt = 0; kt < 8; ++kt)
            a[8 + kt] = *(const bf16x8*)(x1 + kt * 16);
    }

    // stage weights -> LDS (64 KB linear)
    {
        const u16x8* g = (const u16x8*)Wtp;
        u16x8* s = (u16x8*)WS;
#pragma unroll
        for (int i = 0; i < 16; ++i) s[i * 256 + tid] = g[i * 256 + tid];
    }
    __syncthreads();
    if (!act) return;

    f32x16 acc[4];
#pragma unroll
    for (int ct = 0; ct < 4; ++ct)
#pragma unroll
        for (int i = 0; i < 16; ++i) acc[ct][i] = 0.f;

    // 2 ct-chains interleaved per pass for ILP
#pragma unroll
    for (int cp = 0; cp < 2; ++cp) {
        const int c0 = 2 * cp, c1 = 2 * cp + 1;
#pragma unroll
        for (int kt = 0; kt < 16; ++kt) {
            bf16x8 b0 = *(const bf16x8*)&WS[((c0 * 16 + kt) * 64 + lane) * 8];
            bf16x8 b1 = *(const bf16x8*)&WS[((c1 * 16 + kt) * 64 + lane) * 8];
            acc[c0] = __builtin_amdgcn_mfma_f32_32x32x16_bf16(a[kt], b0, acc[c0], 0, 0, 0);
            acc[c1] = __builtin_amdgcn_mfma_f32_32x32x16_bf16(a[kt], b1, acc[c1], 0, 0, 0);
        }
    }

    const int trow0 = gw * 32;
    float bia[4];
#pragma unroll
    for (int ct = 0; ct < 4; ++ct) bia[ct] = bias[ct * 32 + l31];

    if (POOL == 0) {
#pragma unroll
        for (int r = 0; r < 16; ++r) {
            int row = trow0 + (r & 3) + 8 * (r >> 2) + 4 * half;
            float f[4];
            u16x4 pk;
#pragma unroll
            for (int ct = 0; ct < 4; ++ct) {
                f[ct] = fmaxf(acc[ct][r] + bia[ct], 0.f);
                pk[ct] = f2bf(f[ct]);
            }
            *(u16x4*)(outp + (size_t)row * D + l31 * 4) = pk;
            int p8 = __builtin_amdgcn_cvt_pk_fp8_f32(f[0], f[1], 0, false);
            p8 = __builtin_amdgcn_cvt_pk_fp8_f32(f[2], f[3], p8, true);
            *(unsigned int*)(outp8 + (size_t)row * D + l31 * 4) = (unsigned int)p8;
        }
    } else {
        int g[16];
#pragma unroll
        for (int r = 0; r < 16; ++r)
            g[r] = gid[trow0 + (r & 3) + 8 * (r >> 2) + 4 * half];
#pragma unroll
        for (int ct = 0; ct < 4; ++ct) {
            int c = ct * 32 + l31;
            float run = 0.f; int curg = -1;
#pragma unroll
            for (int r = 0; r < 16; ++r) {
                float v = fmaxf(acc[ct][r] + bia[ct], 0.f);
                if (g[r] != curg) {
                    if (curg >= 0) atomicAdd(&gsum[curg * D + c], run);
                    curg = g[r]; run = v;
                } else {
                    run += v;
                }
            }
            if (curg >= 0) atomicAdd(&gsum[curg * D + c], run);
        }
    }
}

// ---------------- final divide ----------------
__global__ void k_final(const float* __restrict__ gsum, const int* __restrict__ gcnt,
                        float* __restrict__ out) {
    int i = blockIdx.x * blockDim.x + threadIdx.x;
    if (i < NUM_GRAPHS * D) {
        int g = i >> 7;
        int c = gcnt[g];
        out[i] = gsum[i] / (float)(c > 0 ? c : 1);
    }
}

// ---------------- launch ----------------
extern "C" void kernel_launch(void* const* d_in, const int* in_sizes, int n_in,
                              void* d_out, int out_size, void* d_ws, size_t ws_size,
                              hipStream_t stream) {
    const float* h   = (const float*)d_in[0];
    const float* W1s = (const float*)d_in[1];
    const float* W1n = (const float*)d_in[2];
    const float* b1  = (const float*)d_in[3];
    const float* W2s = (const float*)d_in[4];
    const float* W2n = (const float*)d_in[5];
    const float* b2  = (const float*)d_in[6];
    const int* src   = (const int*)d_in[7];
    const int* dst   = (const int*)d_in[8];
    const int* gids  = (const int*)d_in[9];
    float* out = (float*)d_out;
    char* ws = (char*)d_ws;

    size_t off = 0;
    auto alloc = [&](size_t bytes) {
        size_t o = off;
        off = (off + bytes + 255) & ~(size_t)255;
        return o;
    };
    // zeroed region (one memset)
    size_t z0         = off;
    size_t gcur_off   = alloc((size_t)NB * 4);
    size_t gsum_off   = alloc((size_t)NUM_GRAPHS * D * 4);
    size_t zlen       = off - z0;
    size_t gcnt_off   = alloc((size_t)NUM_GRAPHS * 4);
    size_t rs_off     = alloc((size_t)N_NODES * 4);
    size_t rl_off     = alloc((size_t)N_NODES * 4);
    size_t bin_off    = alloc((size_t)NB * BUCKET_CAP * 4);
    size_t adj_off    = alloc((size_t)NB * BUCKET_CAP * 4);
    size_t hb_off     = alloc((size_t)N_NODES * D * 2);
    size_t hn_off     = alloc((size_t)N_NODES * D * 2);
    size_t h1_off     = alloc((size_t)N_NODES * D * 2);
    size_t h8_off     = alloc((size_t)N_NODES * D);       // h fp8
    size_t h18_off    = alloc((size_t)N_NODES * D);       // h1 fp8 (permuted cols)
    size_t wt1_off    = alloc((size_t)D * 256 * 2);
    size_t wt2_off    = alloc((size_t)D * 256 * 2);
    (void)ws_size;

    int*   gcur      = (int*)(ws + gcur_off);
    int*   gcnt      = (int*)(ws + gcnt_off);
    float* gsum      = (float*)(ws + gsum_off);
    int*   row_start = (int*)(ws + rs_off);
    int*   row_len   = (int*)(ws + rl_off);
    unsigned int* binned = (unsigned int*)(ws + bin_off);
    int*   adj       = (int*)(ws + adj_off);
    unsigned short* hb  = (unsigned short*)(ws + hb_off);
    unsigned short* hn  = (unsigned short*)(ws + hn_off);
    unsigned short* h1p = (unsigned short*)(ws + h1_off);
    unsigned char*  h8   = (unsigned char*)(ws + h8_off);
    unsigned char*  h1p8 = (unsigned char*)(ws + h18_off);
    unsigned short* Wt1 = (unsigned short*)(ws + wt1_off);
    unsigned short* Wt2 = (unsigned short*)(ws + wt2_off);

    hipMemsetAsync(ws + z0, 0, zlen, stream);

    const int nbin_blocks = (N_EDGES + EPB - 1) / EPB;   // 196

    k_binplace<<<nbin_blocks, 256, 0, stream>>>(src, dst, gcur, binned);
    k_fill2<<<NB, 256, 0, stream>>>(binned, gcur, adj, row_start, row_len);
    k_gcnt_bs<<<1, 128, 0, stream>>>(gids, gcnt);

    k_cast_h<<<(N_NODES * (D / 8) + 255) / 256, 256, 0, stream>>>(h, hb, h8);
    k_prep_w1<<<(D * 256 + 255) / 256, 256, 0, stream>>>(W1s, W1n, Wt1);
    k_prep_w2<<<(D * 256 + 255) / 256, 256, 0, stream>>>(W2s, W2n, Wt2);

    const int agg_blocks = (N_NODES + 15) / 16;    // 6250

    // layer 1
    k_agg_f8<<<agg_blocks, 256, 0, stream>>>(h8, row_start, row_len, adj, hn);
    k_gemm_mfma<0><<<GEMM_BLOCKS, 256, 0, stream>>>(hb, hn, Wt1, b1, h1p, h1p8,
                                                    nullptr, nullptr);
    // layer 2 (pool fused into epilogue)
    k_agg_f8<<<agg_blocks, 256, 0, stream>>>(h1p8, row_start, row_len, adj, hn);
    k_gemm_mfma<1><<<GEMM_BLOCKS, 256, 0, stream>>>(h1p, hn, Wt2, b2, nullptr, nullptr,
                                                    gids, gsum);

    k_final<<<(NUM_GRAPHS * D + 255) / 256, 256, 0, stream>>>(gsum, gcnt, out);
}

// Round 13
// 193.058 us; speedup vs baseline: 1.2397x; 1.0120x over previous
//
#include <hip/hip_runtime.h>

#define N_NODES   100000
#define N_EDGES   1600000
#define D         128
#define NUM_GRAPHS 128

#define NB          196     // dst buckets (512 nodes each)
#define BUCKET_NODES 512
#define BUCKET_CAP  10240
#define EPB         8192    // edges per binplace block

#define N_TILES32   3125    // 100000 / 32 exactly
#define GEMM_BLOCKS 782     // 782 * 4 waves = 3128 >= 3125

typedef __attribute__((ext_vector_type(8)))  short bf16x8;
typedef __attribute__((ext_vector_type(8)))  unsigned short u16x8;
typedef __attribute__((ext_vector_type(4)))  unsigned short u16x4;
typedef __attribute__((ext_vector_type(2)))  unsigned int u32x2;
typedef __attribute__((ext_vector_type(4)))  unsigned int u32x4;
typedef __attribute__((ext_vector_type(16))) float f32x16;

__device__ __forceinline__ float bf2f(unsigned short v) {
    return __uint_as_float(((unsigned int)v) << 16);
}
__device__ __forceinline__ unsigned short f2bf(float f) {
    unsigned int u = __float_as_uint(f);
    u = (u + 0x7FFFu + ((u >> 16) & 1u)) >> 16;
    return (unsigned short)u;
}

// accumulate 8 fp8 (e4m3) values from an 8-byte word pair into acc[0..7]
__device__ __forceinline__ void acc_f8(float* acc, u32x2 v) {
    auto a0 = __builtin_amdgcn_cvt_pk_f32_fp8((int)v[0], false);
    auto a1 = __builtin_amdgcn_cvt_pk_f32_fp8((int)v[0], true);
    auto a2 = __builtin_amdgcn_cvt_pk_f32_fp8((int)v[1], false);
    auto a3 = __builtin_amdgcn_cvt_pk_f32_fp8((int)v[1], true);
    acc[0] += a0[0]; acc[1] += a0[1]; acc[2] += a1[0]; acc[3] += a1[1];
    acc[4] += a2[0]; acc[5] += a2[1]; acc[6] += a3[0]; acc[7] += a3[1];
}

// ---------------- workspace zeroing (replaces slow runtime fillBuffer) ----------------
__global__ void k_zero(u32x4* __restrict__ p, int n16) {
    int i = blockIdx.x * 256 + threadIdx.x;
    if (i < n16) p[i] = (u32x4){0u, 0u, 0u, 0u};
}

// ---------------- edge binning: counting-sort into 196 bucket regions ----------------
__global__ __launch_bounds__(256) void k_binplace(const int* __restrict__ src,
                                                  const int* __restrict__ dst,
                                                  int* __restrict__ gcur,
                                                  unsigned int* __restrict__ binned) {
    __shared__ unsigned int stag[EPB];       // 32 KB
    __shared__ unsigned char sbk[EPB];       // 8 KB
    __shared__ int hist[NB], lstart[NB], lcur[NB], gclaim[NB];
    __shared__ int scan[256];
    const int t = threadIdx.x;
    const int e0 = blockIdx.x * EPB;

    if (t < NB) hist[t] = 0;
    __syncthreads();

    int pk[32]; int bk[32];
#pragma unroll
    for (int i = 0; i < 32; ++i) {
        int e = e0 + t + 256 * i;
        if (e < N_EDGES) {
            int s = src[e], d = dst[e];
            bk[i] = d >> 9;
            pk[i] = (s << 9) | (d & 511);
            atomicAdd(&hist[bk[i]], 1);
        } else {
            bk[i] = -1; pk[i] = 0;
        }
    }
    __syncthreads();

    int hv = (t < NB) ? hist[t] : 0;
    scan[t] = hv;
    __syncthreads();
    for (int off = 1; off < 256; off <<= 1) {
        int add = (t >= off) ? scan[t - off] : 0;
        __syncthreads();
        scan[t] += add;
        __syncthreads();
    }
    if (t < NB) {
        int ex = scan[t] - hv;
        lstart[t] = ex;
        lcur[t]   = ex;
        gclaim[t] = atomicAdd(&gcur[t], hv);
    }
    __syncthreads();

#pragma unroll
    for (int i = 0; i < 32; ++i) {
        if (bk[i] >= 0) {
            int p = atomicAdd(&lcur[bk[i]], 1);
            stag[p] = (unsigned int)pk[i];
            sbk[p] = (unsigned char)bk[i];
        }
    }
    __syncthreads();

    const int total = scan[NB - 1];
    for (int j = t; j < total; j += 256) {
        int b = sbk[j];
        binned[(size_t)b * BUCKET_CAP + gclaim[b] + (j - lstart[b])] = stag[j];
    }
}

// ---------------- per-bucket CSR finalize ----------------
__global__ __launch_bounds__(256) void k_fill2(const unsigned int* __restrict__ binned,
                                               const int* __restrict__ gcur,
                                               int* __restrict__ adj,
                                               int* __restrict__ row_start,
                                               int* __restrict__ row_len) {
    __shared__ int hist[BUCKET_NODES], lstart[BUCKET_NODES], lcur[BUCKET_NODES];
    __shared__ int s2[256];
    const int t = threadIdx.x;
    const int b = blockIdx.x;
    const int C = gcur[b];
    const unsigned int* bp = binned + (size_t)b * BUCKET_CAP;

    hist[t] = 0; hist[t + 256] = 0;
    __syncthreads();
    for (int j = t; j < C; j += 256)
        atomicAdd(&hist[bp[j] & 511], 1);
    __syncthreads();

    int h0 = hist[2 * t], h1 = hist[2 * t + 1];
    int sv = h0 + h1;
    s2[t] = sv;
    __syncthreads();
    for (int off = 1; off < 256; off <<= 1) {
        int add = (t >= off) ? s2[t - off] : 0;
        __syncthreads();
        s2[t] += add;
        __syncthreads();
    }
    int ex = s2[t] - sv;
    lstart[2 * t] = ex;          lcur[2 * t] = ex;
    lstart[2 * t + 1] = ex + h0; lcur[2 * t + 1] = ex + h0;
    __syncthreads();

    for (int dl = t; dl < BUCKET_NODES; dl += 256) {
        int n = b * BUCKET_NODES + dl;
        if (n < N_NODES) {
            row_start[n] = b * BUCKET_CAP + lstart[dl];
            row_len[n]   = hist[dl];
        }
    }

    for (int j = t; j < C; j += 256) {
        unsigned int v = bp[j];
        int dl = v & 511;
        int pos = atomicAdd(&lcur[dl], 1);
        adj[(size_t)b * BUCKET_CAP + pos] = (int)(v >> 9);
    }
}

// graph_ids SORTED -> per-graph count via binary search
__global__ void k_gcnt_bs(const int* __restrict__ gid, int* __restrict__ gcnt) {
    int g = threadIdx.x;
    if (g >= NUM_GRAPHS) return;
    int lo = 0, hi = N_NODES;
    while (lo < hi) { int mid = (lo + hi) >> 1; if (gid[mid] < g) lo = mid + 1; else hi = mid; }
    int beg = lo;
    hi = N_NODES;
    while (lo < hi) { int mid = (lo + hi) >> 1; if (gid[mid] < g + 1) lo = mid + 1; else hi = mid; }
    gcnt[g] = lo - beg;
}

// ---------------- casts / weight prep ----------------

// h fp32 -> bf16 (GEMM self path) + fp8 e4m3 (gather path)
__global__ void k_cast_h(const float* __restrict__ h, unsigned short* __restrict__ hb,
                         unsigned char* __restrict__ h8) {
    int i = blockIdx.x * 256 + threadIdx.x;
    if (i >= N_NODES * (D / 8)) return;
    const float4* hv = (const float4*)h;
    float4 x = hv[2 * i], y = hv[2 * i + 1];
    u16x8 p;
    p[0] = f2bf(x.x); p[1] = f2bf(x.y); p[2] = f2bf(x.z); p[3] = f2bf(x.w);
    p[4] = f2bf(y.x); p[5] = f2bf(y.y); p[6] = f2bf(y.z); p[7] = f2bf(y.w);
    *(u16x8*)(hb + (size_t)i * 8) = p;
    int lo = __builtin_amdgcn_cvt_pk_fp8_f32(x.x, x.y, 0, false);
    lo = __builtin_amdgcn_cvt_pk_fp8_f32(x.z, x.w, lo, true);
    int hi = __builtin_amdgcn_cvt_pk_fp8_f32(y.x, y.y, 0, false);
    hi = __builtin_amdgcn_cvt_pk_fp8_f32(y.z, y.w, hi, true);
    u32x2 q; q[0] = (unsigned int)lo; q[1] = (unsigned int)hi;
    *(u32x2*)(h8 + (size_t)i * 8) = q;
}

// 32x32 fragment-linear weight prep:
//   Wtp[((ct*16+kt)*64 + lane)*8 + j] = W[k][n]
//   n = ct*32 + (lane&31), k = kt*16 + 8*(lane>>5) + j  (k<128 -> Ws, else Wn[k-128])
__global__ void k_prep_w1(const float* __restrict__ Ws, const float* __restrict__ Wn,
                          unsigned short* __restrict__ Wtp) {
    int idx = blockIdx.x * 256 + threadIdx.x;  // 32768
    if (idx >= D * 256) return;
    int j  = idx & 7;
    int l  = (idx >> 3) & 63;
    int fs = idx >> 9;               // ct*16 + kt
    int ct = fs >> 4, kt = fs & 15;
    int n  = ct * 32 + (l & 31);
    int k  = kt * 16 + 8 * (l >> 5) + j;
    float v = (k < 128) ? Ws[k * D + n] : Wn[(k - 128) * D + n];
    Wtp[idx] = f2bf(v);
}

// Layer-1 output stored with column permutation sigma(c) = (c&31)*4 + (c>>5),
// so stored position p holds true col c(p) = 32*(p&3) + (p>>2).
// Layer-2 K axis maps through sigma^-1 (same for self & neigh halves).
__global__ void k_prep_w2(const float* __restrict__ Ws, const float* __restrict__ Wn,
                          unsigned short* __restrict__ Wtp) {
    int idx = blockIdx.x * 256 + threadIdx.x;  // 32768
    if (idx >= D * 256) return;
    int j  = idx & 7;
    int l  = (idx >> 3) & 63;
    int fs = idx >> 9;
    int ct = fs >> 4, kt = fs & 15;
    int n  = ct * 32 + (l & 31);
    int k  = kt * 16 + 8 * (l >> 5) + j;   // 0..255
    int p  = k & 127;
    int c  = 32 * (p & 3) + (p >> 2);      // true column
    float v = (k < 128) ? Ws[c * D + n] : Wn[c * D + n];
    Wtp[idx] = f2bf(v);
}

// ---------------- mean aggregation, fp8 gather (16 lanes/node x 8 B), 8-edge unroll ----
__global__ __launch_bounds__(256) void k_agg_f8(const unsigned char* __restrict__ hin,
                                                const int* __restrict__ row_start,
                                                const int* __restrict__ row_len,
                                                const int* __restrict__ adj,
                                                unsigned short* __restrict__ hout) {
    int node = blockIdx.x * 16 + (threadIdx.x >> 4);
    int sub = threadIdx.x & 15;
    if (node >= N_NODES) return;
    int beg = row_start[node];
    int len = row_len[node];
    int end = beg + len;
    const unsigned char* hsub = hin + sub * 8;   // row stride = D bytes (fp8)
    float acc[8];
#pragma unroll
    for (int i = 0; i < 8; ++i) acc[i] = 0.f;
    int j = beg;
    for (; j + 7 < end; j += 8) {
        u32x2 v0 = *(const u32x2*)(hsub + (size_t)adj[j]     * D);
        u32x2 v1 = *(const u32x2*)(hsub + (size_t)adj[j + 1] * D);
        u32x2 v2 = *(const u32x2*)(hsub + (size_t)adj[j + 2] * D);
        u32x2 v3 = *(const u32x2*)(hsub + (size_t)adj[j + 3] * D);
        u32x2 v4 = *(const u32x2*)(hsub + (size_t)adj[j + 4] * D);
        u32x2 v5 = *(const u32x2*)(hsub + (size_t)adj[j + 5] * D);
        u32x2 v6 = *(const u32x2*)(hsub + (size_t)adj[j + 6] * D);
        u32x2 v7 = *(const u32x2*)(hsub + (size_t)adj[j + 7] * D);
        acc_f8(acc, v0); acc_f8(acc, v1); acc_f8(acc, v2); acc_f8(acc, v3);
        acc_f8(acc, v4); acc_f8(acc, v5); acc_f8(acc, v6); acc_f8(acc, v7);
    }
    for (; j + 3 < end; j += 4) {
        u32x2 v0 = *(const u32x2*)(hsub + (size_t)adj[j]     * D);
        u32x2 v1 = *(const u32x2*)(hsub + (size_t)adj[j + 1] * D);
        u32x2 v2 = *(const u32x2*)(hsub + (size_t)adj[j + 2] * D);
        u32x2 v3 = *(const u32x2*)(hsub + (size_t)adj[j + 3] * D);
        acc_f8(acc, v0); acc_f8(acc, v1); acc_f8(acc, v2); acc_f8(acc, v3);
    }
    for (; j < end; ++j) {
        u32x2 v0 = *(const u32x2*)(hsub + (size_t)adj[j] * D);
        acc_f8(acc, v0);
    }
    float inv = (len > 0) ? 1.f / (float)len : 0.f;
    u16x8 p;
#pragma unroll
    for (int i = 0; i < 8; ++i) p[i] = f2bf(acc[i] * inv);
    *(u16x8*)(hout + (size_t)node * D + sub * 8) = p;
}

// ---------------- MFMA GEMM: 32x32x16, 32 rows/wave, LDS-staged B ----------------
// 782 blocks x 4 waves = 3128 waves; wave gw owns 32-row tile gw (3125 tiles exact).
// A-frag: row = lane&31, k = kt*16 + 8*(lane>>5) + j.
// C/D:    col = lane&31, row = (reg&3) + 8*(reg>>2) + 4*(lane>>5).
// POOL=0: store permuted cols sigma(c)=(c&31)*4+(c>>5) as bf16 (8B/row/lane)
//         PLUS fp8 copy (4B/row/lane) for the layer-2 gather.
// POOL=1: run-compressed per-graph atomics at true cols.
template <int POOL>
__global__ __launch_bounds__(256) void k_gemm_mfma(
    const unsigned short* __restrict__ X0, const unsigned short* __restrict__ X1,
    const unsigned short* __restrict__ Wtp, const float* __restrict__ bias,
    unsigned short* __restrict__ outp, unsigned char* __restrict__ outp8,
    const int* __restrict__ gid, float* __restrict__ gsum) {
    __shared__ unsigned short WS[D * 256];   // 64 KB
    const int tid = threadIdx.x;
    const int wave = tid >> 6, lane = tid & 63;
    const int l31 = lane & 31, half = lane >> 5;
    const int gw = blockIdx.x * 4 + wave;    // 32-row tile id
    const bool act = (gw < N_TILES32);

    // A fragments first (latency hidden under staging barrier)
    bf16x8 a[16];
    if (act) {
        const int row = gw * 32 + l31;
        const unsigned short* x0 = X0 + (size_t)row * D + half * 8;
        const unsigned short* x1 = X1 + (size_t)row * D + half * 8;
#pragma unroll
        for (int kt = 0; kt < 8; ++kt)
            a[kt] = *(const bf16x8*)(x0 + kt * 16);
#pragma unroll
        for (int kt = 0; kt < 8; ++kt)
            a[8 + kt] = *(const bf16x8*)(x1 + kt * 16);
    }

    // stage weights -> LDS (64 KB linear)
    {
        const u16x8* g = (const u16x8*)Wtp;
        u16x8* s = (u16x8*)WS;
#pragma unroll
        for (int i = 0; i < 16; ++i) s[i * 256 + tid] = g[i * 256 + tid];
    }
    __syncthreads();
    if (!act) return;

    f32x16 acc[4];
#pragma unroll
    for (int ct = 0; ct < 4; ++ct)
#pragma unroll
        for (int i = 0; i < 16; ++i) acc[ct][i] = 0.f;

    // 2 ct-chains interleaved per pass for ILP
#pragma unroll
    for (int cp = 0; cp < 2; ++cp) {
        const int c0 = 2 * cp, c1 = 2 * cp + 1;
#pragma unroll
        for (int kt = 0; kt < 16; ++kt) {
            bf16x8 b0 = *(const bf16x8*)&WS[((c0 * 16 + kt) * 64 + lane) * 8];
            bf16x8 b1 = *(const bf16x8*)&WS[((c1 * 16 + kt) * 64 + lane) * 8];
            acc[c0] = __builtin_amdgcn_mfma_f32_32x32x16_bf16(a[kt], b0, acc[c0], 0, 0, 0);
            acc[c1] = __builtin_amdgcn_mfma_f32_32x32x16_bf16(a[kt], b1, acc[c1], 0, 0, 0);
        }
    }

    const int trow0 = gw * 32;
    float bia[4];
#pragma unroll
    for (int ct = 0; ct < 4; ++ct) bia[ct] = bias[ct * 32 + l31];

    if (POOL == 0) {
#pragma unroll
        for (int r = 0; r < 16; ++r) {
            int row = trow0 + (r & 3) + 8 * (r >> 2) + 4 * half;
            float f[4];
            u16x4 pk;
#pragma unroll
            for (int ct = 0; ct < 4; ++ct) {
                f[ct] = fmaxf(acc[ct][r] + bia[ct], 0.f);
                pk[ct] = f2bf(f[ct]);
            }
            *(u16x4*)(outp + (size_t)row * D + l31 * 4) = pk;
            int p8 = __builtin_amdgcn_cvt_pk_fp8_f32(f[0], f[1], 0, false);
            p8 = __builtin_amdgcn_cvt_pk_fp8_f32(f[2], f[3], p8, true);
            *(unsigned int*)(outp8 + (size_t)row * D + l31 * 4) = (unsigned int)p8;
        }
    } else {
        int g[16];
#pragma unroll
        for (int r = 0; r < 16; ++r)
            g[r] = gid[trow0 + (r & 3) + 8 * (r >> 2) + 4 * half];
#pragma unroll
        for (int ct = 0; ct < 4; ++ct) {
            int c = ct * 32 + l31;
            float run = 0.f; int curg = -1;
#pragma unroll
            for (int r = 0; r < 16; ++r) {
                float v = fmaxf(acc[ct][r] + bia[ct], 0.f);
                if (g[r] != curg) {
                    if (curg >= 0) atomicAdd(&gsum[curg * D + c], run);
                    curg = g[r]; run = v;
                } else {
                    run += v;
                }
            }
            if (curg >= 0) atomicAdd(&gsum[curg * D + c], run);
        }
    }
}

// ---------------- final divide ----------------
__global__ void k_final(const float* __restrict__ gsum, const int* __restrict__ gcnt,
                        float* __restrict__ out) {
    int i = blockIdx.x * blockDim.x + threadIdx.x;
    if (i < NUM_GRAPHS * D) {
        int g = i >> 7;
        int c = gcnt[g];
        out[i] = gsum[i] / (float)(c > 0 ? c : 1);
    }
}

// ---------------- launch ----------------
extern "C" void kernel_launch(void* const* d_in, const int* in_sizes, int n_in,
                              void* d_out, int out_size, void* d_ws, size_t ws_size,
                              hipStream_t stream) {
    const float* h   = (const float*)d_in[0];
    const float* W1s = (const float*)d_in[1];
    const float* W1n = (const float*)d_in[2];
    const float* b1  = (const float*)d_in[3];
    const float* W2s = (const float*)d_in[4];
    const float* W2n = (const float*)d_in[5];
    const float* b2  = (const float*)d_in[6];
    const int* src   = (const int*)d_in[7];
    const int* dst   = (const int*)d_in[8];
    const int* gids  = (const int*)d_in[9];
    float* out = (float*)d_out;
    char* ws = (char*)d_ws;

    size_t off = 0;
    auto alloc = [&](size_t bytes) {
        size_t o = off;
        off = (off + bytes + 255) & ~(size_t)255;
        return o;
    };
    // zeroed region (one k_zero launch)
    size_t z0         = off;
    size_t gcur_off   = alloc((size_t)NB * 4);
    size_t gsum_off   = alloc((size_t)NUM_GRAPHS * D * 4);
    size_t zlen       = off - z0;
    size_t gcnt_off   = alloc((size_t)NUM_GRAPHS * 4);
    size_t rs_off     = alloc((size_t)N_NODES * 4);
    size_t rl_off     = alloc((size_t)N_NODES * 4);
    size_t bin_off    = alloc((size_t)NB * BUCKET_CAP * 4);
    size_t adj_off    = alloc((size_t)NB * BUCKET_CAP * 4);
    size_t hb_off     = alloc((size_t)N_NODES * D * 2);
    size_t hn_off     = alloc((size_t)N_NODES * D * 2);
    size_t h1_off     = alloc((size_t)N_NODES * D * 2);
    size_t h8_off     = alloc((size_t)N_NODES * D);       // h fp8
    size_t h18_off    = alloc((size_t)N_NODES * D);       // h1 fp8 (permuted cols)
    size_t wt1_off    = alloc((size_t)D * 256 * 2);
    size_t wt2_off    = alloc((size_t)D * 256 * 2);
    (void)ws_size;

    int*   gcur      = (int*)(ws + gcur_off);
    int*   gcnt      = (int*)(ws + gcnt_off);
    float* gsum      = (float*)(ws + gsum_off);
    int*   row_start = (int*)(ws + rs_off);
    int*   row_len   = (int*)(ws + rl_off);
    unsigned int* binned = (unsigned int*)(ws + bin_off);
    int*   adj       = (int*)(ws + adj_off);
    unsigned short* hb  = (unsigned short*)(ws + hb_off);
    unsigned short* hn  = (unsigned short*)(ws + hn_off);
    unsigned short* h1p = (unsigned short*)(ws + h1_off);
    unsigned char*  h8   = (unsigned char*)(ws + h8_off);
    unsigned char*  h1p8 = (unsigned char*)(ws + h18_off);
    unsigned short* Wt1 = (unsigned short*)(ws + wt1_off);
    unsigned short* Wt2 = (unsigned short*)(ws + wt2_off);

    const int n16 = (int)(zlen / 16);                    // zlen is 256-aligned
    k_zero<<<(n16 + 255) / 256, 256, 0, stream>>>((u32x4*)(ws + z0), n16);

    const int nbin_blocks = (N_EDGES + EPB - 1) / EPB;   // 196

    k_binplace<<<nbin_blocks, 256, 0, stream>>>(src, dst, gcur, binned);
    k_fill2<<<NB, 256, 0, stream>>>(binned, gcur, adj, row_start, row_len);
    k_gcnt_bs<<<1, 128, 0, stream>>>(gids, gcnt);

    k_cast_h<<<(N_NODES * (D / 8) + 255) / 256, 256, 0, stream>>>(h, hb, h8);
    k_prep_w1<<<(D * 256 + 255) / 256, 256, 0, stream>>>(W1s, W1n, Wt1);
    k_prep_w2<<<(D * 256 + 255) / 256, 256, 0, stream>>>(W2s, W2n, Wt2);

    const int agg_blocks = (N_NODES + 15) / 16;    // 6250

    // layer 1
    k_agg_f8<<<agg_blocks, 256, 0, stream>>>(h8, row_start, row_len, adj, hn);
    k_gemm_mfma<0><<<GEMM_BLOCKS, 256, 0, stream>>>(hb, hn, Wt1, b1, h1p, h1p8,
                                                    nullptr, nullptr);
    // layer 2 (pool fused into epilogue)
    k_agg_f8<<<agg_blocks, 256, 0, stream>>>(h1p8, row_start, row_len, adj, hn);
    k_gemm_mfma<1><<<GEMM_BLOCKS, 256, 0, stream>>>(h1p, hn, Wt2, b2, nullptr, nullptr,
                                                    gids, gsum);

    k_final<<<(NUM_GRAPHS * D + 255) / 256, 256, 0, stream>>>(gsum, gcnt, out);
}

// Round 14
// 172.964 us; speedup vs baseline: 1.3837x; 1.1162x over previous
//
#include <hip/hip_runtime.h>

#define N_NODES   100000
#define N_EDGES   1600000
#define D         128
#define NUM_GRAPHS 128

#define NB          196     // dst buckets (512 nodes each)
#define BUCKET_NODES 512
#define BUCKET_CAP  10240
#define EPB         8192    // edges per binplace block

#define N_TILES32   3125    // 100000 / 32 exactly
#define GEMM_BLOCKS 782     // 782 * 4 waves = 3128 >= 3125

typedef __attribute__((ext_vector_type(8)))  short bf16x8;
typedef __attribute__((ext_vector_type(8)))  unsigned short u16x8;
typedef __attribute__((ext_vector_type(4)))  unsigned short u16x4;
typedef __attribute__((ext_vector_type(2)))  unsigned int u32x2;
typedef __attribute__((ext_vector_type(4)))  unsigned int u32x4;
typedef __attribute__((ext_vector_type(16))) float f32x16;

__device__ __forceinline__ float bf2f(unsigned short v) {
    return __uint_as_float(((unsigned int)v) << 16);
}
__device__ __forceinline__ unsigned short f2bf(float f) {
    unsigned int u = __float_as_uint(f);
    u = (u + 0x7FFFu + ((u >> 16) & 1u)) >> 16;
    return (unsigned short)u;
}

// accumulate 8 fp8 (e4m3) values from an 8-byte word pair into acc[0..7]
__device__ __forceinline__ void acc_f8(float* acc, u32x2 v) {
    auto a0 = __builtin_amdgcn_cvt_pk_f32_fp8((int)v[0], false);
    auto a1 = __builtin_amdgcn_cvt_pk_f32_fp8((int)v[0], true);
    auto a2 = __builtin_amdgcn_cvt_pk_f32_fp8((int)v[1], false);
    auto a3 = __builtin_amdgcn_cvt_pk_f32_fp8((int)v[1], true);
    acc[0] += a0[0]; acc[1] += a0[1]; acc[2] += a1[0]; acc[3] += a1[1];
    acc[4] += a2[0]; acc[5] += a2[1]; acc[6] += a3[0]; acc[7] += a3[1];
}

// convert 8 fp8 bytes -> bf16x8 (exact: fp8 values are representable in bf16)
__device__ __forceinline__ bf16x8 f8_to_bf16x8(u32x2 v) {
    auto f0 = __builtin_amdgcn_cvt_pk_f32_fp8((int)v[0], false);
    auto f1 = __builtin_amdgcn_cvt_pk_f32_fp8((int)v[0], true);
    auto f2 = __builtin_amdgcn_cvt_pk_f32_fp8((int)v[1], false);
    auto f3 = __builtin_amdgcn_cvt_pk_f32_fp8((int)v[1], true);
    u16x8 p;
    p[0] = f2bf(f0[0]); p[1] = f2bf(f0[1]); p[2] = f2bf(f1[0]); p[3] = f2bf(f1[1]);
    p[4] = f2bf(f2[0]); p[5] = f2bf(f2[1]); p[6] = f2bf(f3[0]); p[7] = f2bf(f3[1]);
    return *(bf16x8*)&p;
}

// ---------------- merged small kernels: zero | gcnt | prep_w1 | prep_w2 ----------------
// blocks 0..16: zero 66.5 KB region; 17: gcnt binary search; 18..145: Wt1; 146..273: Wt2
__global__ void k_misc(u32x4* __restrict__ zp, int n16,
                       const int* __restrict__ gid, int* __restrict__ gcnt,
                       const float* __restrict__ W1s, const float* __restrict__ W1n,
                       unsigned short* __restrict__ Wt1,
                       const float* __restrict__ W2s, const float* __restrict__ W2n,
                       unsigned short* __restrict__ Wt2) {
    const int b = blockIdx.x;
    if (b < 17) {
        int i = b * 256 + threadIdx.x;
        if (i < n16) zp[i] = (u32x4){0u, 0u, 0u, 0u};
    } else if (b == 17) {
        int g = threadIdx.x;
        if (g >= NUM_GRAPHS) return;
        int lo = 0, hi = N_NODES;
        while (lo < hi) { int mid = (lo + hi) >> 1; if (gid[mid] < g) lo = mid + 1; else hi = mid; }
        int beg = lo;
        hi = N_NODES;
        while (lo < hi) { int mid = (lo + hi) >> 1; if (gid[mid] < g + 1) lo = mid + 1; else hi = mid; }
        gcnt[g] = lo - beg;
    } else if (b < 146) {
        // Wt1[((ct*16+kt)*64+l)*8+j] = W[k][n], n=ct*32+(l&31), k=kt*16+8*(l>>5)+j
        int idx = (b - 18) * 256 + threadIdx.x;
        int j  = idx & 7;
        int l  = (idx >> 3) & 63;
        int fs = idx >> 9;
        int ct = fs >> 4, kt = fs & 15;
        int n  = ct * 32 + (l & 31);
        int k  = kt * 16 + 8 * (l >> 5) + j;
        float v = (k < 128) ? W1s[k * D + n] : W1n[(k - 128) * D + n];
        Wt1[idx] = f2bf(v);
    } else {
        // Wt2: K axis through sigma^-1: stored pos p holds true col c = 32*(p&3)+(p>>2)
        int idx = (b - 146) * 256 + threadIdx.x;
        int j  = idx & 7;
        int l  = (idx >> 3) & 63;
        int fs = idx >> 9;
        int ct = fs >> 4, kt = fs & 15;
        int n  = ct * 32 + (l & 31);
        int k  = kt * 16 + 8 * (l >> 5) + j;
        int p  = k & 127;
        int c  = 32 * (p & 3) + (p >> 2);
        float v = (k < 128) ? W2s[c * D + n] : W2n[c * D + n];
        Wt2[idx] = f2bf(v);
    }
}

// ---------------- edge binning: counting-sort into 196 bucket regions ----------------
__global__ __launch_bounds__(256) void k_binplace(const int* __restrict__ src,
                                                  const int* __restrict__ dst,
                                                  int* __restrict__ gcur,
                                                  unsigned int* __restrict__ binned) {
    __shared__ unsigned int stag[EPB];       // 32 KB
    __shared__ unsigned char sbk[EPB];       // 8 KB
    __shared__ int hist[NB], lstart[NB], lcur[NB], gclaim[NB];
    __shared__ int scan[256];
    const int t = threadIdx.x;
    const int e0 = blockIdx.x * EPB;

    if (t < NB) hist[t] = 0;
    __syncthreads();

    int pk[32]; int bk[32];
#pragma unroll
    for (int i = 0; i < 32; ++i) {
        int e = e0 + t + 256 * i;
        if (e < N_EDGES) {
            int s = src[e], d = dst[e];
            bk[i] = d >> 9;
            pk[i] = (s << 9) | (d & 511);
            atomicAdd(&hist[bk[i]], 1);
        } else {
            bk[i] = -1; pk[i] = 0;
        }
    }
    __syncthreads();

    int hv = (t < NB) ? hist[t] : 0;
    scan[t] = hv;
    __syncthreads();
    for (int off = 1; off < 256; off <<= 1) {
        int add = (t >= off) ? scan[t - off] : 0;
        __syncthreads();
        scan[t] += add;
        __syncthreads();
    }
    if (t < NB) {
        int ex = scan[t] - hv;
        lstart[t] = ex;
        lcur[t]   = ex;
        gclaim[t] = atomicAdd(&gcur[t], hv);
    }
    __syncthreads();

#pragma unroll
    for (int i = 0; i < 32; ++i) {
        if (bk[i] >= 0) {
            int p = atomicAdd(&lcur[bk[i]], 1);
            stag[p] = (unsigned int)pk[i];
            sbk[p] = (unsigned char)bk[i];
        }
    }
    __syncthreads();

    const int total = scan[NB - 1];
    for (int j = t; j < total; j += 256) {
        int b = sbk[j];
        binned[(size_t)b * BUCKET_CAP + gclaim[b] + (j - lstart[b])] = stag[j];
    }
}

// ---------------- per-bucket CSR finalize ----------------
__global__ __launch_bounds__(256) void k_fill2(const unsigned int* __restrict__ binned,
                                               const int* __restrict__ gcur,
                                               int* __restrict__ adj,
                                               int* __restrict__ row_start,
                                               int* __restrict__ row_len) {
    __shared__ int hist[BUCKET_NODES], lstart[BUCKET_NODES], lcur[BUCKET_NODES];
    __shared__ int s2[256];
    const int t = threadIdx.x;
    const int b = blockIdx.x;
    const int C = gcur[b];
    const unsigned int* bp = binned + (size_t)b * BUCKET_CAP;

    hist[t] = 0; hist[t + 256] = 0;
    __syncthreads();
    for (int j = t; j < C; j += 256)
        atomicAdd(&hist[bp[j] & 511], 1);
    __syncthreads();

    int h0 = hist[2 * t], h1 = hist[2 * t + 1];
    int sv = h0 + h1;
    s2[t] = sv;
    __syncthreads();
    for (int off = 1; off < 256; off <<= 1) {
        int add = (t >= off) ? s2[t - off] : 0;
        __syncthreads();
        s2[t] += add;
        __syncthreads();
    }
    int ex = s2[t] - sv;
    lstart[2 * t] = ex;          lcur[2 * t] = ex;
    lstart[2 * t + 1] = ex + h0; lcur[2 * t + 1] = ex + h0;
    __syncthreads();

    for (int dl = t; dl < BUCKET_NODES; dl += 256) {
        int n = b * BUCKET_NODES + dl;
        if (n < N_NODES) {
            row_start[n] = b * BUCKET_CAP + lstart[dl];
            row_len[n]   = hist[dl];
        }
    }

    for (int j = t; j < C; j += 256) {
        unsigned int v = bp[j];
        int dl = v & 511;
        int pos = atomicAdd(&lcur[dl], 1);
        adj[(size_t)b * BUCKET_CAP + pos] = (int)(v >> 9);
    }
}

// ---------------- h fp32 -> fp8 e4m3 (single activation precision) ----------------
__global__ void k_cast_h(const float* __restrict__ h, unsigned char* __restrict__ h8) {
    int i = blockIdx.x * 256 + threadIdx.x;
    if (i >= N_NODES * (D / 8)) return;
    const float4* hv = (const float4*)h;
    float4 x = hv[2 * i], y = hv[2 * i + 1];
    int lo = __builtin_amdgcn_cvt_pk_fp8_f32(x.x, x.y, 0, false);
    lo = __builtin_amdgcn_cvt_pk_fp8_f32(x.z, x.w, lo, true);
    int hi = __builtin_amdgcn_cvt_pk_fp8_f32(y.x, y.y, 0, false);
    hi = __builtin_amdgcn_cvt_pk_fp8_f32(y.z, y.w, hi, true);
    u32x2 q; q[0] = (unsigned int)lo; q[1] = (unsigned int)hi;
    *(u32x2*)(h8 + (size_t)i * 8) = q;
}

// ---------------- mean aggregation, fp8 gather (16 lanes/node x 8 B), 8-edge unroll ----
__global__ __launch_bounds__(256) void k_agg_f8(const unsigned char* __restrict__ hin,
                                                const int* __restrict__ row_start,
                                                const int* __restrict__ row_len,
                                                const int* __restrict__ adj,
                                                unsigned short* __restrict__ hout) {
    int node = blockIdx.x * 16 + (threadIdx.x >> 4);
    int sub = threadIdx.x & 15;
    if (node >= N_NODES) return;
    int beg = row_start[node];
    int len = row_len[node];
    int end = beg + len;
    const unsigned char* hsub = hin + sub * 8;   // row stride = D bytes (fp8)
    float acc[8];
#pragma unroll
    for (int i = 0; i < 8; ++i) acc[i] = 0.f;
    int j = beg;
    for (; j + 7 < end; j += 8) {
        u32x2 v0 = *(const u32x2*)(hsub + (size_t)adj[j]     * D);
        u32x2 v1 = *(const u32x2*)(hsub + (size_t)adj[j + 1] * D);
        u32x2 v2 = *(const u32x2*)(hsub + (size_t)adj[j + 2] * D);
        u32x2 v3 = *(const u32x2*)(hsub + (size_t)adj[j + 3] * D);
        u32x2 v4 = *(const u32x2*)(hsub + (size_t)adj[j + 4] * D);
        u32x2 v5 = *(const u32x2*)(hsub + (size_t)adj[j + 5] * D);
        u32x2 v6 = *(const u32x2*)(hsub + (size_t)adj[j + 6] * D);
        u32x2 v7 = *(const u32x2*)(hsub + (size_t)adj[j + 7] * D);
        acc_f8(acc, v0); acc_f8(acc, v1); acc_f8(acc, v2); acc_f8(acc, v3);
        acc_f8(acc, v4); acc_f8(acc, v5); acc_f8(acc, v6); acc_f8(acc, v7);
    }
    for (; j + 3 < end; j += 4) {
        u32x2 v0 = *(const u32x2*)(hsub + (size_t)adj[j]     * D);
        u32x2 v1 = *(const u32x2*)(hsub + (size_t)adj[j + 1] * D);
        u32x2 v2 = *(const u32x2*)(hsub + (size_t)adj[j + 2] * D);
        u32x2 v3 = *(const u32x2*)(hsub + (size_t)adj[j + 3] * D);
        acc_f8(acc, v0); acc_f8(acc, v1); acc_f8(acc, v2); acc_f8(acc, v3);
    }
    for (; j < end; ++j) {
        u32x2 v0 = *(const u32x2*)(hsub + (size_t)adj[j] * D);
        acc_f8(acc, v0);
    }
    float inv = (len > 0) ? 1.f / (float)len : 0.f;
    u16x8 p;
#pragma unroll
    for (int i = 0; i < 8; ++i) p[i] = f2bf(acc[i] * inv);
    *(u16x8*)(hout + (size_t)node * D + sub * 8) = p;
}

// ---------------- MFMA GEMM: 32x32x16, 32 rows/wave, LDS-staged B ----------------
// X0 is fp8 (self activations), converted to bf16 A-frags in registers.
// X1 (aggregated neighbors) stays bf16.
// A-frag: row = lane&31, k = kt*16 + 8*(lane>>5) + j.
// C/D:    col = lane&31, row = (reg&3) + 8*(reg>>2) + 4*(lane>>5).
// POOL=0: store fp8 only, cols sigma-permuted: pos l31*4+ct holds col ct*32+l31.
// POOL=1: run-compressed per-graph atomics at true cols.
template <int POOL>
__global__ __launch_bounds__(256) void k_gemm_mfma(
    const unsigned char* __restrict__ X0, const unsigned short* __restrict__ X1,
    const unsigned short* __restrict__ Wtp, const float* __restrict__ bias,
    unsigned char* __restrict__ outp8,
    const int* __restrict__ gid, float* __restrict__ gsum) {
    __shared__ unsigned short WS[D * 256];   // 64 KB
    const int tid = threadIdx.x;
    const int wave = tid >> 6, lane = tid & 63;
    const int l31 = lane & 31, half = lane >> 5;
    const int gw = blockIdx.x * 4 + wave;    // 32-row tile id
    const bool act = (gw < N_TILES32);

    // A fragments first (latency hidden under staging barrier)
    bf16x8 a[16];
    if (act) {
        const int row = gw * 32 + l31;
        const unsigned char*  x0 = X0 + (size_t)row * D + half * 8;  // fp8 bytes
        const unsigned short* x1 = X1 + (size_t)row * D + half * 8;  // bf16
        u32x2 v8[8];
#pragma unroll
        for (int kt = 0; kt < 8; ++kt)
            v8[kt] = *(const u32x2*)(x0 + kt * 16);
#pragma unroll
        for (int kt = 0; kt < 8; ++kt)
            a[8 + kt] = *(const bf16x8*)(x1 + kt * 16);
#pragma unroll
        for (int kt = 0; kt < 8; ++kt)
            a[kt] = f8_to_bf16x8(v8[kt]);
    }

    // stage weights -> LDS (64 KB linear)
    {
        const u16x8* g = (const u16x8*)Wtp;
        u16x8* s = (u16x8*)WS;
#pragma unroll
        for (int i = 0; i < 16; ++i) s[i * 256 + tid] = g[i * 256 + tid];
    }
    __syncthreads();
    if (!act) return;

    f32x16 acc[4];
#pragma unroll
    for (int ct = 0; ct < 4; ++ct)
#pragma unroll
        for (int i = 0; i < 16; ++i) acc[ct][i] = 0.f;

    // 2 ct-chains interleaved per pass for ILP
#pragma unroll
    for (int cp = 0; cp < 2; ++cp) {
        const int c0 = 2 * cp, c1 = 2 * cp + 1;
#pragma unroll
        for (int kt = 0; kt < 16; ++kt) {
            bf16x8 b0 = *(const bf16x8*)&WS[((c0 * 16 + kt) * 64 + lane) * 8];
            bf16x8 b1 = *(const bf16x8*)&WS[((c1 * 16 + kt) * 64 + lane) * 8];
            acc[c0] = __builtin_amdgcn_mfma_f32_32x32x16_bf16(a[kt], b0, acc[c0], 0, 0, 0);
            acc[c1] = __builtin_amdgcn_mfma_f32_32x32x16_bf16(a[kt], b1, acc[c1], 0, 0, 0);
        }
    }

    const int trow0 = gw * 32;
    float bia[4];
#pragma unroll
    for (int ct = 0; ct < 4; ++ct) bia[ct] = bias[ct * 32 + l31];

    if (POOL == 0) {
#pragma unroll
        for (int r = 0; r < 16; ++r) {
            int row = trow0 + (r & 3) + 8 * (r >> 2) + 4 * half;
            float f[4];
#pragma unroll
            for (int ct = 0; ct < 4; ++ct)
                f[ct] = fmaxf(acc[ct][r] + bia[ct], 0.f);
            int p8 = __builtin_amdgcn_cvt_pk_fp8_f32(f[0], f[1], 0, false);
            p8 = __builtin_amdgcn_cvt_pk_fp8_f32(f[2], f[3], p8, true);
            *(unsigned int*)(outp8 + (size_t)row * D + l31 * 4) = (unsigned int)p8;
        }
    } else {
        int g[16];
#pragma unroll
        for (int r = 0; r < 16; ++r)
            g[r] = gid[trow0 + (r & 3) + 8 * (r >> 2) + 4 * half];
#pragma unroll
        for (int ct = 0; ct < 4; ++ct) {
            int c = ct * 32 + l31;
            float run = 0.f; int curg = -1;
#pragma unroll
            for (int r = 0; r < 16; ++r) {
                float v = fmaxf(acc[ct][r] + bia[ct], 0.f);
                if (g[r] != curg) {
                    if (curg >= 0) atomicAdd(&gsum[curg * D + c], run);
                    curg = g[r]; run = v;
                } else {
                    run += v;
                }
            }
            if (curg >= 0) atomicAdd(&gsum[curg * D + c], run);
        }
    }
}

// ---------------- final divide ----------------
__global__ void k_final(const float* __restrict__ gsum, const int* __restrict__ gcnt,
                        float* __restrict__ out) {
    int i = blockIdx.x * blockDim.x + threadIdx.x;
    if (i < NUM_GRAPHS * D) {
        int g = i >> 7;
        int c = gcnt[g];
        out[i] = gsum[i] / (float)(c > 0 ? c : 1);
    }
}

// ---------------- launch ----------------
extern "C" void kernel_launch(void* const* d_in, const int* in_sizes, int n_in,
                              void* d_out, int out_size, void* d_ws, size_t ws_size,
                              hipStream_t stream) {
    const float* h   = (const float*)d_in[0];
    const float* W1s = (const float*)d_in[1];
    const float* W1n = (const float*)d_in[2];
    const float* b1  = (const float*)d_in[3];
    const float* W2s = (const float*)d_in[4];
    const float* W2n = (const float*)d_in[5];
    const float* b2  = (const float*)d_in[6];
    const int* src   = (const int*)d_in[7];
    const int* dst   = (const int*)d_in[8];
    const int* gids  = (const int*)d_in[9];
    float* out = (float*)d_out;
    char* ws = (char*)d_ws;

    size_t off = 0;
    auto alloc = [&](size_t bytes) {
        size_t o = off;
        off = (off + bytes + 255) & ~(size_t)255;
        return o;
    };
    // zeroed region (by k_misc blocks 0..16)
    size_t z0         = off;
    size_t gcur_off   = alloc((size_t)NB * 4);
    size_t gsum_off   = alloc((size_t)NUM_GRAPHS * D * 4);
    size_t zlen       = off - z0;
    size_t gcnt_off   = alloc((size_t)NUM_GRAPHS * 4);
    size_t rs_off     = alloc((size_t)N_NODES * 4);
    size_t rl_off     = alloc((size_t)N_NODES * 4);
    size_t bin_off    = alloc((size_t)NB * BUCKET_CAP * 4);
    size_t adj_off    = alloc((size_t)NB * BUCKET_CAP * 4);
    size_t hn_off     = alloc((size_t)N_NODES * D * 2);   // aggregated neigh, bf16
    size_t h8_off     = alloc((size_t)N_NODES * D);       // h fp8
    size_t h18_off    = alloc((size_t)N_NODES * D);       // h1 fp8 (sigma-permuted cols)
    size_t wt1_off    = alloc((size_t)D * 256 * 2);
    size_t wt2_off    = alloc((size_t)D * 256 * 2);
    (void)ws_size;

    int*   gcur      = (int*)(ws + gcur_off);
    int*   gcnt      = (int*)(ws + gcnt_off);
    float* gsum      = (float*)(ws + gsum_off);
    int*   row_start = (int*)(ws + rs_off);
    int*   row_len   = (int*)(ws + rl_off);
    unsigned int* binned = (unsigned int*)(ws + bin_off);
    int*   adj       = (int*)(ws + adj_off);
    unsigned short* hn  = (unsigned short*)(ws + hn_off);
    unsigned char*  h8   = (unsigned char*)(ws + h8_off);
    unsigned char*  h1p8 = (unsigned char*)(ws + h18_off);
    unsigned short* Wt1 = (unsigned short*)(ws + wt1_off);
    unsigned short* Wt2 = (unsigned short*)(ws + wt2_off);

    const int n16 = (int)(zlen / 16);   // 66560/16 = 4160 -> 17 zero-blocks

    // merged: zero(17) | gcnt(1) | prep_w1(128) | prep_w2(128) = 274 blocks
    k_misc<<<274, 256, 0, stream>>>((u32x4*)(ws + z0), n16, gids, gcnt,
                                    W1s, W1n, Wt1, W2s, W2n, Wt2);

    const int nbin_blocks = (N_EDGES + EPB - 1) / EPB;   // 196
    k_binplace<<<nbin_blocks, 256, 0, stream>>>(src, dst, gcur, binned);
    k_fill2<<<NB, 256, 0, stream>>>(binned, gcur, adj, row_start, row_len);

    k_cast_h<<<(N_NODES * (D / 8) + 255) / 256, 256, 0, stream>>>(h, h8);

    const int agg_blocks = (N_NODES + 15) / 16;    // 6250

    // layer 1
    k_agg_f8<<<agg_blocks, 256, 0, stream>>>(h8, row_start, row_len, adj, hn);
    k_gemm_mfma<0><<<GEMM_BLOCKS, 256, 0, stream>>>(h8, hn, Wt1, b1, h1p8,
                                                    nullptr, nullptr);
    // layer 2 (pool fused into epilogue)
    k_agg_f8<<<agg_blocks, 256, 0, stream>>>(h1p8, row_start, row_len, adj, hn);
    k_gemm_mfma<1><<<GEMM_BLOCKS, 256, 0, stream>>>(h1p8, hn, Wt2, b2, nullptr,
                                                    gids, gsum);

    k_final<<<(NUM_GRAPHS * D + 255) / 256, 256, 0, stream>>>(gsum, gcnt, out);
}

// Round 15
// 167.686 us; speedup vs baseline: 1.4272x; 1.0315x over previous
//
#include <hip/hip_runtime.h>

#define N_NODES   100000
#define N_EDGES   1600000
#define D         128
#define NUM_GRAPHS 128

#define NB          196     // dst buckets (512 nodes each)
#define BUCKET_NODES 512
#define BUCKET_CAP  10240
#define EPB         8192    // edges per binplace block

#define N_TILES32   3125    // 100000 / 32 exactly
#define GEMM_BLOCKS 782     // 782 * 4 waves = 3128 >= 3125

typedef __attribute__((ext_vector_type(8)))  short bf16x8;
typedef __attribute__((ext_vector_type(8)))  unsigned short u16x8;
typedef __attribute__((ext_vector_type(2)))  unsigned int u32x2;
typedef __attribute__((ext_vector_type(4)))  unsigned int u32x4;
typedef __attribute__((ext_vector_type(16))) float f32x16;

__device__ __forceinline__ unsigned short f2bf(float f) {
    unsigned int u = __float_as_uint(f);
    u = (u + 0x7FFFu + ((u >> 16) & 1u)) >> 16;
    return (unsigned short)u;
}

// accumulate 8 fp8 (e4m3) values from an 8-byte word pair into acc[0..7]
__device__ __forceinline__ void acc_f8(float* acc, u32x2 v) {
    auto a0 = __builtin_amdgcn_cvt_pk_f32_fp8((int)v[0], false);
    auto a1 = __builtin_amdgcn_cvt_pk_f32_fp8((int)v[0], true);
    auto a2 = __builtin_amdgcn_cvt_pk_f32_fp8((int)v[1], false);
    auto a3 = __builtin_amdgcn_cvt_pk_f32_fp8((int)v[1], true);
    acc[0] += a0[0]; acc[1] += a0[1]; acc[2] += a1[0]; acc[3] += a1[1];
    acc[4] += a2[0]; acc[5] += a2[1]; acc[6] += a3[0]; acc[7] += a3[1];
}

// 8 fp8 bytes -> bf16x8, exact (e4m3 mantissa subset of bf16), via v_perm packing
__device__ __forceinline__ bf16x8 f8_to_bf16x8(u32x2 v) {
    auto f0 = __builtin_amdgcn_cvt_pk_f32_fp8((int)v[0], false);
    auto f1 = __builtin_amdgcn_cvt_pk_f32_fp8((int)v[0], true);
    auto f2 = __builtin_amdgcn_cvt_pk_f32_fp8((int)v[1], false);
    auto f3 = __builtin_amdgcn_cvt_pk_f32_fp8((int)v[1], true);
    u32x4 w;
    w[0] = __builtin_amdgcn_perm(__float_as_uint(f0[1]), __float_as_uint(f0[0]), 0x07060302u);
    w[1] = __builtin_amdgcn_perm(__float_as_uint(f1[1]), __float_as_uint(f1[0]), 0x07060302u);
    w[2] = __builtin_amdgcn_perm(__float_as_uint(f2[1]), __float_as_uint(f2[0]), 0x07060302u);
    w[3] = __builtin_amdgcn_perm(__float_as_uint(f3[1]), __float_as_uint(f3[0]), 0x07060302u);
    return *(bf16x8*)&w;
}

// ---------------- merged small kernels: zero | gcnt | prep_w1 | prep_w2 | cast ----------
// blocks 0..16: zero; 17: gcnt; 18..145: Wt1; 146..273: Wt2; 274..6523: h fp32->fp8
__global__ void k_misc(u32x4* __restrict__ zp, int n16,
                       const int* __restrict__ gid, int* __restrict__ gcnt,
                       const float* __restrict__ W1s, const float* __restrict__ W1n,
                       unsigned short* __restrict__ Wt1,
                       const float* __restrict__ W2s, const float* __restrict__ W2n,
                       unsigned short* __restrict__ Wt2,
                       const float* __restrict__ h, unsigned char* __restrict__ h8) {
    const int b = blockIdx.x;
    if (b < 17) {
        int i = b * 256 + threadIdx.x;
        if (i < n16) zp[i] = (u32x4){0u, 0u, 0u, 0u};
    } else if (b == 17) {
        int g = threadIdx.x;
        if (g >= NUM_GRAPHS) return;
        int lo = 0, hi = N_NODES;
        while (lo < hi) { int mid = (lo + hi) >> 1; if (gid[mid] < g) lo = mid + 1; else hi = mid; }
        int beg = lo;
        hi = N_NODES;
        while (lo < hi) { int mid = (lo + hi) >> 1; if (gid[mid] < g + 1) lo = mid + 1; else hi = mid; }
        gcnt[g] = lo - beg;
    } else if (b < 146) {
        // Wt1[((ct*16+kt)*64+l)*8+j] = W[k][n], n=ct*32+(l&31), k=kt*16+8*(l>>5)+j
        int idx = (b - 18) * 256 + threadIdx.x;
        int j  = idx & 7;
        int l  = (idx >> 3) & 63;
        int fs = idx >> 9;
        int ct = fs >> 4, kt = fs & 15;
        int n  = ct * 32 + (l & 31);
        int k  = kt * 16 + 8 * (l >> 5) + j;
        float v = (k < 128) ? W1s[k * D + n] : W1n[(k - 128) * D + n];
        Wt1[idx] = f2bf(v);
    } else if (b < 274) {
        // Wt2: K axis through sigma^-1: stored pos p holds true col c = 32*(p&3)+(p>>2)
        int idx = (b - 146) * 256 + threadIdx.x;
        int j  = idx & 7;
        int l  = (idx >> 3) & 63;
        int fs = idx >> 9;
        int ct = fs >> 4, kt = fs & 15;
        int n  = ct * 32 + (l & 31);
        int k  = kt * 16 + 8 * (l >> 5) + j;
        int p  = k & 127;
        int c  = 32 * (p & 3) + (p >> 2);
        float v = (k < 128) ? W2s[c * D + n] : W2n[c * D + n];
        Wt2[idx] = f2bf(v);
    } else {
        int i = (b - 274) * 256 + threadIdx.x;
        if (i >= N_NODES * (D / 8)) return;
        const float4* hv = (const float4*)h;
        float4 x = hv[2 * i], y = hv[2 * i + 1];
        int lo = __builtin_amdgcn_cvt_pk_fp8_f32(x.x, x.y, 0, false);
        lo = __builtin_amdgcn_cvt_pk_fp8_f32(x.z, x.w, lo, true);
        int hi = __builtin_amdgcn_cvt_pk_fp8_f32(y.x, y.y, 0, false);
        hi = __builtin_amdgcn_cvt_pk_fp8_f32(y.z, y.w, hi, true);
        u32x2 q; q[0] = (unsigned int)lo; q[1] = (unsigned int)hi;
        *(u32x2*)(h8 + (size_t)i * 8) = q;
    }
}

// ---------------- edge binning: counting-sort into 196 bucket regions ----------------
__global__ __launch_bounds__(256) void k_binplace(const int* __restrict__ src,
                                                  const int* __restrict__ dst,
                                                  int* __restrict__ gcur,
                                                  unsigned int* __restrict__ binned) {
    __shared__ unsigned int stag[EPB];       // 32 KB
    __shared__ unsigned char sbk[EPB];       // 8 KB
    __shared__ int hist[NB], lstart[NB], lcur[NB], gclaim[NB];
    __shared__ int scan[256];
    const int t = threadIdx.x;
    const int e0 = blockIdx.x * EPB;

    if (t < NB) hist[t] = 0;
    __syncthreads();

    int pk[32]; int bk[32];
#pragma unroll
    for (int i = 0; i < 32; ++i) {
        int e = e0 + t + 256 * i;
        if (e < N_EDGES) {
            int s = src[e], d = dst[e];
            bk[i] = d >> 9;
            pk[i] = (s << 9) | (d & 511);
            atomicAdd(&hist[bk[i]], 1);
        } else {
            bk[i] = -1; pk[i] = 0;
        }
    }
    __syncthreads();

    int hv = (t < NB) ? hist[t] : 0;
    scan[t] = hv;
    __syncthreads();
    for (int off = 1; off < 256; off <<= 1) {
        int add = (t >= off) ? scan[t - off] : 0;
        __syncthreads();
        scan[t] += add;
        __syncthreads();
    }
    if (t < NB) {
        int ex = scan[t] - hv;
        lstart[t] = ex;
        lcur[t]   = ex;
        gclaim[t] = atomicAdd(&gcur[t], hv);
    }
    __syncthreads();

#pragma unroll
    for (int i = 0; i < 32; ++i) {
        if (bk[i] >= 0) {
            int p = atomicAdd(&lcur[bk[i]], 1);
            stag[p] = (unsigned int)pk[i];
            sbk[p] = (unsigned char)bk[i];
        }
    }
    __syncthreads();

    const int total = scan[NB - 1];
    for (int j = t; j < total; j += 256) {
        int b = sbk[j];
        binned[(size_t)b * BUCKET_CAP + gclaim[b] + (j - lstart[b])] = stag[j];
    }
}

// ---------------- per-bucket CSR finalize ----------------
__global__ __launch_bounds__(256) void k_fill2(const unsigned int* __restrict__ binned,
                                               const int* __restrict__ gcur,
                                               int* __restrict__ adj,
                                               int* __restrict__ row_start,
                                               int* __restrict__ row_len) {
    __shared__ int hist[BUCKET_NODES], lstart[BUCKET_NODES], lcur[BUCKET_NODES];
    __shared__ int s2[256];
    const int t = threadIdx.x;
    const int b = blockIdx.x;
    const int C = gcur[b];
    const unsigned int* bp = binned + (size_t)b * BUCKET_CAP;

    hist[t] = 0; hist[t + 256] = 0;
    __syncthreads();
    for (int j = t; j < C; j += 256)
        atomicAdd(&hist[bp[j] & 511], 1);
    __syncthreads();

    int h0 = hist[2 * t], h1 = hist[2 * t + 1];
    int sv = h0 + h1;
    s2[t] = sv;
    __syncthreads();
    for (int off = 1; off < 256; off <<= 1) {
        int add = (t >= off) ? s2[t - off] : 0;
        __syncthreads();
        s2[t] += add;
        __syncthreads();
    }
    int ex = s2[t] - sv;
    lstart[2 * t] = ex;          lcur[2 * t] = ex;
    lstart[2 * t + 1] = ex + h0; lcur[2 * t + 1] = ex + h0;
    __syncthreads();

    for (int dl = t; dl < BUCKET_NODES; dl += 256) {
        int n = b * BUCKET_NODES + dl;
        if (n < N_NODES) {
            row_start[n] = b * BUCKET_CAP + lstart[dl];
            row_len[n]   = hist[dl];
        }
    }

    for (int j = t; j < C; j += 256) {
        unsigned int v = bp[j];
        int dl = v & 511;
        int pos = atomicAdd(&lcur[dl], 1);
        adj[(size_t)b * BUCKET_CAP + pos] = (int)(v >> 9);
    }
}

// ---------------- mean aggregation, fp8 in / fp8 out, 8-edge unroll ----------------
__global__ __launch_bounds__(256) void k_agg_f8(const unsigned char* __restrict__ hin,
                                                const int* __restrict__ row_start,
                                                const int* __restrict__ row_len,
                                                const int* __restrict__ adj,
                                                unsigned char* __restrict__ hout) {
    int node = blockIdx.x * 16 + (threadIdx.x >> 4);
    int sub = threadIdx.x & 15;
    if (node >= N_NODES) return;
    int beg = row_start[node];
    int len = row_len[node];
    int end = beg + len;
    const unsigned char* hsub = hin + sub * 8;   // row stride = D bytes (fp8)
    float acc[8];
#pragma unroll
    for (int i = 0; i < 8; ++i) acc[i] = 0.f;
    int j = beg;
    for (; j + 7 < end; j += 8) {
        u32x2 v0 = *(const u32x2*)(hsub + (size_t)adj[j]     * D);
        u32x2 v1 = *(const u32x2*)(hsub + (size_t)adj[j + 1] * D);
        u32x2 v2 = *(const u32x2*)(hsub + (size_t)adj[j + 2] * D);
        u32x2 v3 = *(const u32x2*)(hsub + (size_t)adj[j + 3] * D);
        u32x2 v4 = *(const u32x2*)(hsub + (size_t)adj[j + 4] * D);
        u32x2 v5 = *(const u32x2*)(hsub + (size_t)adj[j + 5] * D);
        u32x2 v6 = *(const u32x2*)(hsub + (size_t)adj[j + 6] * D);
        u32x2 v7 = *(const u32x2*)(hsub + (size_t)adj[j + 7] * D);
        acc_f8(acc, v0); acc_f8(acc, v1); acc_f8(acc, v2); acc_f8(acc, v3);
        acc_f8(acc, v4); acc_f8(acc, v5); acc_f8(acc, v6); acc_f8(acc, v7);
    }
    for (; j + 3 < end; j += 4) {
        u32x2 v0 = *(const u32x2*)(hsub + (size_t)adj[j]     * D);
        u32x2 v1 = *(const u32x2*)(hsub + (size_t)adj[j + 1] * D);
        u32x2 v2 = *(const u32x2*)(hsub + (size_t)adj[j + 2] * D);
        u32x2 v3 = *(const u32x2*)(hsub + (size_t)adj[j + 3] * D);
        acc_f8(acc, v0); acc_f8(acc, v1); acc_f8(acc, v2); acc_f8(acc, v3);
    }
    for (; j < end; ++j) {
        u32x2 v0 = *(const u32x2*)(hsub + (size_t)adj[j] * D);
        acc_f8(acc, v0);
    }
    float inv = (len > 0) ? 1.f / (float)len : 0.f;
    int lo = __builtin_amdgcn_cvt_pk_fp8_f32(acc[0] * inv, acc[1] * inv, 0, false);
    lo = __builtin_amdgcn_cvt_pk_fp8_f32(acc[2] * inv, acc[3] * inv, lo, true);
    int hi = __builtin_amdgcn_cvt_pk_fp8_f32(acc[4] * inv, acc[5] * inv, 0, false);
    hi = __builtin_amdgcn_cvt_pk_fp8_f32(acc[6] * inv, acc[7] * inv, hi, true);
    u32x2 q; q[0] = (unsigned int)lo; q[1] = (unsigned int)hi;
    *(u32x2*)(hout + (size_t)node * D + sub * 8) = q;
}

// ---------------- MFMA GEMM: 32x32x16, 32 rows/wave, LDS-staged B ----------------
// X0 (self) and X1 (agg neigh) both fp8, converted to bf16 A-frags in registers.
// A-frag: row = lane&31, k = kt*16 + 8*(lane>>5) + j.
// C/D:    col = lane&31, row = (reg&3) + 8*(reg>>2) + 4*(lane>>5).
// POOL=0: store fp8, cols sigma-permuted: pos l31*4+ct holds col ct*32+l31.
// POOL=1: run-compressed per-graph atomics at true cols.
template <int POOL>
__global__ __launch_bounds__(256) void k_gemm_mfma(
    const unsigned char* __restrict__ X0, const unsigned char* __restrict__ X1,
    const unsigned short* __restrict__ Wtp, const float* __restrict__ bias,
    unsigned char* __restrict__ outp8,
    const int* __restrict__ gid, float* __restrict__ gsum) {
    __shared__ unsigned short WS[D * 256];   // 64 KB
    const int tid = threadIdx.x;
    const int wave = tid >> 6, lane = tid & 63;
    const int l31 = lane & 31, half = lane >> 5;
    const int gw = blockIdx.x * 4 + wave;    // 32-row tile id
    const bool act = (gw < N_TILES32);

    // A fragments first (latency hidden under staging barrier)
    bf16x8 a[16];
    if (act) {
        const int row = gw * 32 + l31;
        const unsigned char* x0 = X0 + (size_t)row * D + half * 8;
        const unsigned char* x1 = X1 + (size_t)row * D + half * 8;
        u32x2 v8[16];
#pragma unroll
        for (int kt = 0; kt < 8; ++kt)
            v8[kt] = *(const u32x2*)(x0 + kt * 16);
#pragma unroll
        for (int kt = 0; kt < 8; ++kt)
            v8[8 + kt] = *(const u32x2*)(x1 + kt * 16);
#pragma unroll
        for (int kt = 0; kt < 16; ++kt)
            a[kt] = f8_to_bf16x8(v8[kt]);
    }

    // stage weights -> LDS (64 KB linear)
    {
        const u16x8* g = (const u16x8*)Wtp;
        u16x8* s = (u16x8*)WS;
#pragma unroll
        for (int i = 0; i < 16; ++i) s[i * 256 + tid] = g[i * 256 + tid];
    }
    __syncthreads();
    if (!act) return;

    f32x16 acc[4];
#pragma unroll
    for (int ct = 0; ct < 4; ++ct)
#pragma unroll
        for (int i = 0; i < 16; ++i) acc[ct][i] = 0.f;

    // 2 ct-chains interleaved per pass for ILP
#pragma unroll
    for (int cp = 0; cp < 2; ++cp) {
        const int c0 = 2 * cp, c1 = 2 * cp + 1;
#pragma unroll
        for (int kt = 0; kt < 16; ++kt) {
            bf16x8 b0 = *(const bf16x8*)&WS[((c0 * 16 + kt) * 64 + lane) * 8];
            bf16x8 b1 = *(const bf16x8*)&WS[((c1 * 16 + kt) * 64 + lane) * 8];
            acc[c0] = __builtin_amdgcn_mfma_f32_32x32x16_bf16(a[kt], b0, acc[c0], 0, 0, 0);
            acc[c1] = __builtin_amdgcn_mfma_f32_32x32x16_bf16(a[kt], b1, acc[c1], 0, 0, 0);
        }
    }

    const int trow0 = gw * 32;
    float bia[4];
#pragma unroll
    for (int ct = 0; ct < 4; ++ct) bia[ct] = bias[ct * 32 + l31];

    if (POOL == 0) {
#pragma unroll
        for (int r = 0; r < 16; ++r) {
            int row = trow0 + (r & 3) + 8 * (r >> 2) + 4 * half;
            float f[4];
#pragma unroll
            for (int ct = 0; ct < 4; ++ct)
                f[ct] = fmaxf(acc[ct][r] + bia[ct], 0.f);
            int p8 = __builtin_amdgcn_cvt_pk_fp8_f32(f[0], f[1], 0, false);
            p8 = __builtin_amdgcn_cvt_pk_fp8_f32(f[2], f[3], p8, true);
            *(unsigned int*)(outp8 + (size_t)row * D + l31 * 4) = (unsigned int)p8;
        }
    } else {
        int g[16];
#pragma unroll
        for (int r = 0; r < 16; ++r)
            g[r] = gid[trow0 + (r & 3) + 8 * (r >> 2) + 4 * half];
#pragma unroll
        for (int ct = 0; ct < 4; ++ct) {
            int c = ct * 32 + l31;
            float run = 0.f; int curg = -1;
#pragma unroll
            for (int r = 0; r < 16; ++r) {
                float v = fmaxf(acc[ct][r] + bia[ct], 0.f);
                if (g[r] != curg) {
                    if (curg >= 0) atomicAdd(&gsum[curg * D + c], run);
                    curg = g[r]; run = v;
                } else {
                    run += v;
                }
            }
            if (curg >= 0) atomicAdd(&gsum[curg * D + c], run);
        }
    }
}

// ---------------- final divide ----------------
__global__ void k_final(const float* __restrict__ gsum, const int* __restrict__ gcnt,
                        float* __restrict__ out) {
    int i = blockIdx.x * blockDim.x + threadIdx.x;
    if (i < NUM_GRAPHS * D) {
        int g = i >> 7;
        int c = gcnt[g];
        out[i] = gsum[i] / (float)(c > 0 ? c : 1);
    }
}

// ---------------- launch ----------------
extern "C" void kernel_launch(void* const* d_in, const int* in_sizes, int n_in,
                              void* d_out, int out_size, void* d_ws, size_t ws_size,
                              hipStream_t stream) {
    const float* h   = (const float*)d_in[0];
    const float* W1s = (const float*)d_in[1];
    const float* W1n = (const float*)d_in[2];
    const float* b1  = (const float*)d_in[3];
    const float* W2s = (const float*)d_in[4];
    const float* W2n = (const float*)d_in[5];
    const float* b2  = (const float*)d_in[6];
    const int* src   = (const int*)d_in[7];
    const int* dst   = (const int*)d_in[8];
    const int* gids  = (const int*)d_in[9];
    float* out = (float*)d_out;
    char* ws = (char*)d_ws;

    size_t off = 0;
    auto alloc = [&](size_t bytes) {
        size_t o = off;
        off = (off + bytes + 255) & ~(size_t)255;
        return o;
    };
    // zeroed region (by k_misc blocks 0..16)
    size_t z0         = off;
    size_t gcur_off   = alloc((size_t)NB * 4);
    size_t gsum_off   = alloc((size_t)NUM_GRAPHS * D * 4);
    size_t zlen       = off - z0;
    size_t gcnt_off   = alloc((size_t)NUM_GRAPHS * 4);
    size_t rs_off     = alloc((size_t)N_NODES * 4);
    size_t rl_off     = alloc((size_t)N_NODES * 4);
    size_t bin_off    = alloc((size_t)NB * BUCKET_CAP * 4);
    size_t adj_off    = alloc((size_t)NB * BUCKET_CAP * 4);
    size_t hn_off     = alloc((size_t)N_NODES * D);       // aggregated neigh, fp8
    size_t h8_off     = alloc((size_t)N_NODES * D);       // h fp8
    size_t h18_off    = alloc((size_t)N_NODES * D);       // h1 fp8 (sigma-permuted cols)
    size_t wt1_off    = alloc((size_t)D * 256 * 2);
    size_t wt2_off    = alloc((size_t)D * 256 * 2);
    (void)ws_size;

    int*   gcur      = (int*)(ws + gcur_off);
    int*   gcnt      = (int*)(ws + gcnt_off);
    float* gsum      = (float*)(ws + gsum_off);
    int*   row_start = (int*)(ws + rs_off);
    int*   row_len   = (int*)(ws + rl_off);
    unsigned int* binned = (unsigned int*)(ws + bin_off);
    int*   adj       = (int*)(ws + adj_off);
    unsigned char*  hn8  = (unsigned char*)(ws + hn_off);
    unsigned char*  h8   = (unsigned char*)(ws + h8_off);
    unsigned char*  h1p8 = (unsigned char*)(ws + h18_off);
    unsigned short* Wt1 = (unsigned short*)(ws + wt1_off);
    unsigned short* Wt2 = (unsigned short*)(ws + wt2_off);

    const int n16 = (int)(zlen / 16);   // 17 zero-blocks

    // merged: zero(17) | gcnt(1) | prep_w1(128) | prep_w2(128) | cast(6250) = 6524
    k_misc<<<6524, 256, 0, stream>>>((u32x4*)(ws + z0), n16, gids, gcnt,
                                     W1s, W1n, Wt1, W2s, W2n, Wt2, h, h8);

    const int nbin_blocks = (N_EDGES + EPB - 1) / EPB;   // 196
    k_binplace<<<nbin_blocks, 256, 0, stream>>>(src, dst, gcur, binned);
    k_fill2<<<NB, 256, 0, stream>>>(binned, gcur, adj, row_start, row_len);

    const int agg_blocks = (N_NODES + 15) / 16;    // 6250

    // layer 1
    k_agg_f8<<<agg_blocks, 256, 0, stream>>>(h8, row_start, row_len, adj, hn8);
    k_gemm_mfma<0><<<GEMM_BLOCKS, 256, 0, stream>>>(h8, hn8, Wt1, b1, h1p8,
                                                    nullptr, nullptr);
    // layer 2 (pool fused into epilogue)
    k_agg_f8<<<agg_blocks, 256, 0, stream>>>(h1p8, row_start, row_len, adj, hn8);
    k_gemm_mfma<1><<<GEMM_BLOCKS, 256, 0, stream>>>(h1p8, hn8, Wt2, b2, nullptr,
                                                    gids, gsum);

    k_final<<<(NUM_GRAPHS * D + 255) / 256, 256, 0, stream>>>(gsum, gcnt, out);
}